// Round 1
// baseline (440.337 us; speedup 1.0000x reference)
//
#include <hip/hip_runtime.h>
#include <hip/hip_bf16.h>
#include <math.h>

#define BB 64
#define NN 128
#define DD 32
#define PP (NN * (NN - 1))   // 16256
#define EPSF 1e-5f
#define GRID 1024

typedef __attribute__((ext_vector_type(8))) short bf16x8;
typedef __attribute__((ext_vector_type(4))) float f32x4;

static __device__ __forceinline__ unsigned short f2bf(float x) {
    unsigned u = __builtin_bit_cast(unsigned, x);
    u += 0x7fff + ((u >> 16) & 1);          // RNE
    return (unsigned short)(u >> 16);
}
static __device__ __forceinline__ unsigned pk2bf(float a, float b) {
    float2 t; t.x = a; t.y = b;
    __hip_bfloat162 h = __float22bfloat162_rn(t);   // v_cvt_pk_bf16_f32
    unsigned u;
    __builtin_memcpy(&u, &h, 4);
    return u;
}
static __device__ __forceinline__ float leakyf(float x) {
    return fmaxf(x, 0.01f * x);
}

// Device-scope grid barrier. Requires all GRID blocks co-resident
// (guaranteed: __launch_bounds__(256,4) => 4 blocks/CU * 256 CUs = 1024).
// s_barrier drains vmcnt(0) so every thread's stores reached L2 before the
// leader's agent-scope release (buffer_wbl2); the acquire spin emits
// buffer_inv so stale L1/L2 lines are dropped before phase N+1 reads.
static __device__ __forceinline__ void grid_sync(unsigned* cnt) {
    __syncthreads();
    if (threadIdx.x == 0) {
        __hip_atomic_fetch_add(cnt, 1u, __ATOMIC_ACQ_REL, __HIP_MEMORY_SCOPE_AGENT);
        while (__hip_atomic_load(cnt, __ATOMIC_ACQUIRE, __HIP_MEMORY_SCOPE_AGENT)
               < (unsigned)GRID)
            __builtin_amdgcn_s_sleep(8);
    }
    __syncthreads();
}

__global__ __launch_bounds__(256, 4) void fused_kernel(
    const float* __restrict__ inputs, const float* __restrict__ W1,
    const float* __restrict__ b1, const float* __restrict__ g1,
    const float* __restrict__ be1, const float* __restrict__ W2,
    const float* __restrict__ b2, const float* __restrict__ W3,
    const float* __restrict__ b3, const float* __restrict__ Wf1,
    const float* __restrict__ bf1, const float* __restrict__ gf,
    const float* __restrict__ bef, const float* __restrict__ Wf2,
    const float* __restrict__ bf2,
    float* __restrict__ AT, float* __restrict__ BT,
    unsigned short* __restrict__ ATh, unsigned short* __restrict__ BTh,
    float* __restrict__ SQp, float* __restrict__ statA, float* __restrict__ statB,
    float* __restrict__ f, float* __restrict__ fpartA, float* __restrict__ fpartB,
    unsigned short* __restrict__ W2p, unsigned short* __restrict__ W3p,
    float* __restrict__ edges_out, float* __restrict__ outp,
    unsigned* __restrict__ cnt)
{
    // phase-union scratch: proj needs 10368 B (max), edges 9216, stats 4096, out 2688
    __shared__ __align__(16) char smem[10368];
    int tid = threadIdx.x;
    int bx = blockIdx.x;
    int lane = tid & 63, w = tid >> 6;

    // ================= Phase 1: proj + per-node partial sums + pack + zero ===
    if (bx < 512) {
        float* Xs  = (float*)smem;           // 16*33
        float* W1s = (float*)smem + 528;     // 2048
        float* red = (float*)smem + 2576;    // 16
        int n = bx >> 2, q = bx & 3;

        for (int idx = tid; idx < 2048; idx += 256) W1s[idx] = W1[idx];
        for (int idx = tid; idx < 512; idx += 256) {
            int r = idx >> 5, d = idx & 31;
            Xs[r * 33 + d] = inputs[(size_t)(q * 16 + r) * 4096 + n * 32 + d];
        }
        __syncthreads();

        int j = tid & 31, rb = tid >> 5;
        float b1j = b1[j];
        float sa = 0.f, qa = 0.f, sb = 0.f, qb = 0.f;
        #pragma unroll
        for (int i = 0; i < 2; ++i) {
            int r = rb * 2 + i;
            int b = q * 16 + r;
            float a = b1j, c = 0.f;
            #pragma unroll
            for (int k = 0; k < 32; ++k) {
                float x = Xs[r * 33 + k];
                a += x * W1s[k * 32 + j];
                c += x * W1s[(32 + k) * 32 + j];
            }
            size_t off = ((size_t)n * 64 + b) * 32 + j;
            AT[off] = a;  BT[off] = c;
            ATh[off] = f2bf(a);  BTh[off] = f2bf(c);
            sa += a; qa += a * a; sb += c; qb += c * c;
        }
        #pragma unroll
        for (int d = 32; d > 0; d >>= 1) {
            sa += __shfl_down(sa, d, 64);
            qa += __shfl_down(qa, d, 64);
            sb += __shfl_down(sb, d, 64);
            qb += __shfl_down(qb, d, 64);
        }
        if (lane == 0) { red[w*4+0] = sa; red[w*4+1] = qa; red[w*4+2] = sb; red[w*4+3] = qb; }
        __syncthreads();
        if (tid == 0) {
            float4 v;
            v.x = red[0] + red[4] + red[8]  + red[12];
            v.y = red[1] + red[5] + red[9]  + red[13];
            v.z = red[2] + red[6] + red[10] + red[14];
            v.w = red[3] + red[7] + red[11] + red[15];
            ((float4*)SQp)[n * 4 + q] = v;
        }
    } else if (bx == 512) {
        if (tid < 64) {      // pack W2/W3 -> bf16 B-frag layout
            int l = tid, nn2 = l & 15, kc = l >> 4;
            #pragma unroll
            for (int ct = 0; ct < 2; ++ct)
                #pragma unroll
                for (int jj = 0; jj < 8; ++jj) {
                    int k = kc * 8 + jj;
                    W2p[(ct * 64 + l) * 8 + jj] = f2bf(W2[k * 32 + ct * 16 + nn2]);
                }
            #pragma unroll
            for (int ct = 0; ct < 3; ++ct)
                #pragma unroll
                for (int jj = 0; jj < 8; ++jj) {
                    int k = kc * 8 + jj;
                    int c2 = ct * 16 + nn2;
                    W3p[(ct * 64 + l) * 8 + jj] = f2bf(c2 < 33 ? W3[k * 33 + c2] : 0.f);
                }
        }
    } else if (bx == 513) {
        for (int idx = tid; idx < 1024; idx += 256) {
            fpartA[idx] = 0.f;
            fpartB[idx] = 0.f;
        }
    }

    grid_sync(cnt + 0);

    // ================= Phase 2: LN stats via bf16 MFMA cross-GEMM ===========
    if (bx < 64) {
        float* part = (float*)smem;          // 4*64*4 floats
        int s0 = (bx >> 3) * 16, t0 = (bx & 7) * 16;
        int m = lane & 15, kc = lane >> 4;
        const unsigned short* abase = ATh + (size_t)(s0 + m) * 2048 + kc * 8 + w * 512;
        const unsigned short* bbase = BTh + (size_t)(t0 + m) * 2048 + kc * 8 + w * 512;

        f32x4 acc0 = {0.f, 0.f, 0.f, 0.f}, acc1 = {0.f, 0.f, 0.f, 0.f};
        #pragma unroll
        for (int step = 0; step < 8; ++step) {
            bf16x8 av0 = *(const bf16x8*)(abase + (2 * step) * 32);
            bf16x8 bv0 = *(const bf16x8*)(bbase + (2 * step) * 32);
            acc0 = __builtin_amdgcn_mfma_f32_16x16x32_bf16(av0, bv0, acc0, 0, 0, 0);
            bf16x8 av1 = *(const bf16x8*)(abase + (2 * step + 1) * 32);
            bf16x8 bv1 = *(const bf16x8*)(bbase + (2 * step + 1) * 32);
            acc1 = __builtin_amdgcn_mfma_f32_16x16x32_bf16(av1, bv1, acc1, 0, 0, 0);
        }
        f32x4 acc;
        acc[0] = acc0[0] + acc1[0]; acc[1] = acc0[1] + acc1[1];
        acc[2] = acc0[2] + acc1[2]; acc[3] = acc0[3] + acc1[3];
        *(f32x4*)&part[(w * 64 + lane) * 4] = acc;
        __syncthreads();

        if (w == 0) {
            #pragma unroll
            for (int ww = 1; ww < 4; ++ww) {
                f32x4 o2 = *(const f32x4*)&part[(ww * 64 + lane) * 4];
                acc[0] += o2[0]; acc[1] += o2[1]; acc[2] += o2[2]; acc[3] += o2[3];
            }
            int col = lane & 15, quad = lane >> 4;
            int t = t0 + col;
            float sbt = 0.f, qbt = 0.f;
            #pragma unroll
            for (int o2 = 0; o2 < 4; ++o2) {
                float4 v = ((const float4*)SQp)[t * 4 + o2];
                sbt += v.z; qbt += v.w;
            }
            #pragma unroll
            for (int r = 0; r < 4; ++r) {
                int s = s0 + quad * 4 + r;
                if (s != t) {
                    float sas = 0.f, qas = 0.f;
                    #pragma unroll
                    for (int o2 = 0; o2 < 4; ++o2) {
                        float4 v = ((const float4*)SQp)[s * 4 + o2];
                        sas += v.x; qas += v.y;
                    }
                    int e = t - (t > s);
                    int p = s * 127 + e;
                    float S = sas + sbt;
                    float Q = qas + qbt + 2.f * acc[r];
                    float mean = S * (1.f / 2048.f);
                    float var  = Q * (1.f / 2048.f) - mean * mean;
                    float inv  = rsqrtf(var + EPSF);
                    float sc   = inv * g1[p];
                    statA[p] = sc;
                    statB[p] = be1[p] - mean * sc;
                }
            }
        }
    }

    grid_sync(cnt + 1);

    // ================= Phase 3: edge MLP, 8 virtual blocks per real block ===
    // real block bx -> batch bb2 = bx>>4, s = (bx&15)*8 + vi, vi = 0..7.
    // Same b across the 8 s-values: BT rows re-hit L1/L2; Wf1/W2p/W3p/bias
    // loads amortized 8x. aggbuf parity-double-buffered: 1 barrier per vi.
    {
        unsigned short (*Hs)[512] = (unsigned short (*)[512])smem;   // 4096 B
        float* Wf1s = (float*)(smem + 4096);                         // 4096 B
        float (*aggbuf)[4][32] = (float (*)[4][32])(smem + 8192);    // 1024 B

        int m = lane & 15;          // A-frag row within tile / C-frag col
        int kb = lane >> 4;         // k-block (8 wide)
        int col = m;
        int q4 = kb * 4;            // C-frag row group
        int qbase = lane & 48;

        for (int idx = tid; idx < 1024; idx += 256) Wf1s[idx] = Wf1[idx];

        bf16x8 wb2[2], wb3[3];
        wb2[0] = *(const bf16x8*)(W2p + (0 * 64 + lane) * 8);
        wb2[1] = *(const bf16x8*)(W2p + (1 * 64 + lane) * 8);
        wb3[0] = *(const bf16x8*)(W3p + (0 * 64 + lane) * 8);
        wb3[1] = *(const bf16x8*)(W3p + (1 * 64 + lane) * 8);
        wb3[2] = *(const bf16x8*)(W3p + (2 * 64 + lane) * 8);
        float b2c0 = b2[col], b2c1 = b2[16 + col];
        float b3c[3];
        #pragma unroll
        for (int ct = 0; ct < 3; ++ct) {
            int c = ct * 16 + col;
            b3c[ct] = (c < 33) ? b3[c] : 0.f;
        }

        int bb2 = bx >> 4;
        int sbase = (bx & 15) * 8;

        for (int vi = 0; vi < 8; ++vi) {
            int s = sbase + vi;
            const float4* asl = (const float4*)(AT + ((size_t)s * 64 + bb2) * 32 + kb * 8);
            float4 a0 = asl[0], a1 = asl[1];

            float aggpart[3] = {0.f, 0.f, 0.f};

            #pragma unroll
            for (int rt = 0; rt < 2; ++rt) {
                int tile = w * 2 + rt;
                int e = tile * 16 + m;
                bool valid = (e < 127);
                int ee = valid ? e : 0;
                int t = ee + (ee >= s);
                int p = s * 127 + ee;
                float sc = statA[p], sh = statB[p];

                const float4* bsl = (const float4*)(BT + ((size_t)t * 64 + bb2) * 32 + kb * 8);
                float4 bv0 = bsl[0], bv1 = bsl[1];

                float nh[8];
                nh[0] = leakyf((a0.x + bv0.x) * sc + sh);
                nh[1] = leakyf((a0.y + bv0.y) * sc + sh);
                nh[2] = leakyf((a0.z + bv0.z) * sc + sh);
                nh[3] = leakyf((a0.w + bv0.w) * sc + sh);
                nh[4] = leakyf((a1.x + bv1.x) * sc + sh);
                nh[5] = leakyf((a1.y + bv1.y) * sc + sh);
                nh[6] = leakyf((a1.z + bv1.z) * sc + sh);
                nh[7] = leakyf((a1.w + bv1.w) * sc + sh);
                if (!valid) {
                    #pragma unroll
                    for (int q = 0; q < 8; ++q) nh[q] = 0.f;
                }
                union { bf16x8 v; unsigned u[4]; } AF;
                #pragma unroll
                for (int q = 0; q < 4; ++q) AF.u[q] = pk2bf(nh[2*q], nh[2*q+1]);

                // GEMM2
                f32x4 c0 = {0.f, 0.f, 0.f, 0.f}, c1 = {0.f, 0.f, 0.f, 0.f};
                c0 = __builtin_amdgcn_mfma_f32_16x16x32_bf16(AF.v, wb2[0], c0, 0, 0, 0);
                c1 = __builtin_amdgcn_mfma_f32_16x16x32_bf16(AF.v, wb2[1], c1, 0, 0, 0);

                // C -> A transpose via wave-private swizzled scratch (no barrier)
                #pragma unroll
                for (int reg = 0; reg < 4; ++reg) {
                    int row = q4 + reg;
                    float x = leakyf(c0[reg] + b2c0);
                    float y = leakyf(c1[reg] + b2c1);
                    int cA = col;
                    int cB = col + 16;
                    Hs[w][row * 32 + (((cA >> 3) ^ (row >> 2)) & 3) * 8 + (cA & 7)] = f2bf(x);
                    Hs[w][row * 32 + (((cB >> 3) ^ (row >> 2)) & 3) * 8 + (cB & 7)] = f2bf(y);
                }
                bf16x8 a2 = *(const bf16x8*)&Hs[w][m * 32 + ((kb ^ (m >> 2)) & 3) * 8];

                // GEMM3
                f32x4 oo[3];
                #pragma unroll
                for (int ct = 0; ct < 3; ++ct) {
                    f32x4 cc = {0.f, 0.f, 0.f, 0.f};
                    oo[ct] = __builtin_amdgcn_mfma_f32_16x16x32_bf16(a2, wb3[ct], cc, 0, 0, 0);
                }

                float v0 = 0.f, v1 = 0.f, v2 = 0.f, v3 = 0.f;
                int grow0 = tile * 16 + q4;
                if (col == 0) {
                    v0 = 1.f / (1.f + __expf(-(oo[0][0] + b3c[0])));
                    v1 = 1.f / (1.f + __expf(-(oo[0][1] + b3c[0])));
                    v2 = 1.f / (1.f + __expf(-(oo[0][2] + b3c[0])));
                    v3 = (grow0 == 124) ? 0.f
                       : 1.f / (1.f + __expf(-(oo[0][3] + b3c[0])));
                    float* ep = edges_out + (size_t)bb2 * PP + s * 127 + grow0;
                    ep[0] = v0; ep[1] = v1; ep[2] = v2;
                    if (grow0 != 124) ep[3] = v3;
                }
                float ev0 = __shfl(v0, qbase, 64);
                float ev1 = __shfl(v1, qbase, 64);
                float ev2 = __shfl(v2, qbase, 64);
                float ev3 = __shfl(v3, qbase, 64);

                #pragma unroll
                for (int ct = 0; ct < 3; ++ct) {
                    float bb3 = b3c[ct];
                    float pt = ev0 * (oo[ct][0] + bb3) + ev1 * (oo[ct][1] + bb3)
                             + ev2 * (oo[ct][2] + bb3) + ev3 * (oo[ct][3] + bb3);
                    aggpart[ct] += pt;
                }
            }

            int par = vi & 1;
            #pragma unroll
            for (int ct = 0; ct < 3; ++ct) {
                float pt = aggpart[ct];
                pt += __shfl_xor(pt, 16, 64);
                pt += __shfl_xor(pt, 32, 64);
                int c = ct * 16 + col;
                if (kb == 0 && c >= 1 && c <= 32) aggbuf[par][w][c - 1] = pt;
            }
            __syncthreads();    // one barrier per vi (parity keeps vi+1 writes safe)

            // f-row tail: rotate the working wave so tails balance across waves
            if (w == (vi & 3) && lane < 16) {
                int j = lane;
                size_t row = (size_t)bb2 * 128 + s;
                const float* xrow = inputs + row * 32;
                float acc = bf1[j];
                #pragma unroll
                for (int k = 0; k < 32; ++k) acc += xrow[k] * Wf1s[k * 16 + j];
                #pragma unroll
                for (int k = 0; k < 32; ++k) {
                    float tot = aggbuf[par][0][k] + aggbuf[par][1][k]
                              + aggbuf[par][2][k] + aggbuf[par][3][k];
                    acc += tot * Wf1s[(32 + k) * 16 + j];
                }
                f[row * 16 + j] = acc;
                int bucket = s & 63;
                atomicAdd(&fpartA[bucket * 16 + j], acc);
                atomicAdd(&fpartB[bucket * 16 + j], acc * acc);
            }
        }
    }

    grid_sync(cnt + 2);

    // ================= Phase 4: f-stats reduce (redundant) + out =============
    {
        float* Wf2s = (float*)smem;              // 512
        float* scv  = (float*)smem + 512;        // 16
        float* shv  = (float*)smem + 528;        // 16
        float* fs   = (float*)smem + 544;        // 128

        for (int idx = tid; idx < 512; idx += 256) Wf2s[idx] = Wf2[idx];
        if (tid < 16) {
            float S = 0.f, Q = 0.f;
            #pragma unroll
            for (int g = 0; g < 64; ++g) {
                S += fpartA[g * 16 + tid];
                Q += fpartB[g * 16 + tid];
            }
            float mean = S * (1.f / 8192.f);
            float var  = Q * (1.f / 8192.f) - mean * mean;
            float inv  = rsqrtf(var + EPSF);
            float s2   = inv * gf[tid];
            scv[tid] = s2;
            shv[tid] = bef[tid] - mean * s2;
        }
        int row0 = bx * 8;
        if (tid < 128) {
            int r = tid >> 4, j = tid & 15;
            fs[r * 16 + j] = f[(size_t)(row0 + r) * 16 + j];
        }
        __syncthreads();

        int rl = tid >> 5, d = tid & 31;
        float acc = bf2[d];
        #pragma unroll
        for (int j2 = 0; j2 < 16; ++j2) {
            float v = fs[rl * 16 + j2] * scv[j2] + shv[j2];
            v = leakyf(v);
            acc += v * Wf2s[j2 * 32 + d];
        }
        outp[(size_t)(row0 + rl) * 32 + d] = acc;
    }
}

extern "C" void kernel_launch(void* const* d_in, const int* in_sizes, int n_in,
                              void* d_out, int out_size, void* d_ws, size_t ws_size,
                              hipStream_t stream) {
    const float* inputs = (const float*)d_in[0];
    const float* W1   = (const float*)d_in[3];
    const float* b1   = (const float*)d_in[4];
    const float* g1   = (const float*)d_in[5];
    const float* be1  = (const float*)d_in[6];
    const float* W2   = (const float*)d_in[7];
    const float* b2   = (const float*)d_in[8];
    const float* W3   = (const float*)d_in[9];
    const float* b3   = (const float*)d_in[10];
    const float* Wf1  = (const float*)d_in[11];
    const float* bf1  = (const float*)d_in[12];
    const float* gf   = (const float*)d_in[13];
    const float* bef  = (const float*)d_in[14];
    const float* Wf2  = (const float*)d_in[15];
    const float* bf2  = (const float*)d_in[16];

    float* ws = (float*)d_ws;
    float* AT     = ws;                              // 262144
    float* BT     = ws + 262144;                     // 262144
    unsigned short* ATh = (unsigned short*)(ws + 524288);  // 262144 ush
    unsigned short* BTh = ATh + 262144;                    // 262144 ush
    float* SQp    = ws + 786432;                     // 2048 slot (2044 used)
    float* statA  = ws + 790528;                     // 16256
    float* statB  = ws + 806784;                     // 16256
    float* f      = ws + 823040;                     // 131072
    float* fpartA = ws + 954112;                     // 1024
    float* fpartB = ws + 955136;                     // 1024
    unsigned short* W2p = (unsigned short*)(ws + 956160);  // 1024 ush
    unsigned short* W3p = W2p + 1024;                      // 1536 ush
    // grid-sync counters in SQp slack (floats 788480..790527 unused)
    unsigned* cnt = (unsigned*)(ws + 788480);

    float* edges_out = (float*)d_out;                    // B*P
    float* outp      = edges_out + (size_t)BB * PP;      // B*N*D

    hipMemsetAsync(cnt, 0, 16, stream);
    fused_kernel<<<GRID, 256, 0, stream>>>(
        inputs, W1, b1, g1, be1, W2, b2, W3, b3, Wf1, bf1, gf, bef, Wf2, bf2,
        AT, BT, ATh, BTh, SQp, statA, statB, f, fpartA, fpartB, W2p, W3p,
        edges_out, outp, cnt);
}

// Round 2
// 208.968 us; speedup vs baseline: 2.1072x; 2.1072x over previous
//
#include <hip/hip_runtime.h>
#include <hip/hip_bf16.h>
#include <math.h>

#define BB 64
#define NN 128
#define DD 32
#define PP (NN * (NN - 1))   // 16256
#define EPSF 1e-5f
#define GRID 1024

typedef __attribute__((ext_vector_type(8))) short bf16x8;
typedef __attribute__((ext_vector_type(4))) float f32x4;
typedef __attribute__((ext_vector_type(2))) float f32x2;

static __device__ __forceinline__ unsigned short f2bf(float x) {
    unsigned u = __builtin_bit_cast(unsigned, x);
    u += 0x7fff + ((u >> 16) & 1);          // RNE
    return (unsigned short)(u >> 16);
}
static __device__ __forceinline__ unsigned pk2bf(float a, float b) {
    float2 t; t.x = a; t.y = b;
    __hip_bfloat162 h = __float22bfloat162_rn(t);   // v_cvt_pk_bf16_f32
    unsigned u;
    __builtin_memcpy(&u, &h, 4);
    return u;
}
static __device__ __forceinline__ float leakyf(float x) {
    return fmaxf(x, 0.01f * x);
}

// ---------------- grid barrier v2 -----------------
// Arrival: release fence + RELAXED fetch_add striped over 4 cachelines
// (relaxed far-atomics pipeline at the MALL; no acq_rel RMW convoy).
// Block 0 alone polls the counters (relaxed + s_sleep), then acq_rel fence
// and writes 4 replicated flag lines. Everyone else spins RELAXED on a
// read-only flag line -> no per-poll invalidates. One acquire fence at exit.
// State: 128 dwords per barrier (4 cnt lines + 4 flag lines, 64 B each),
// zeroed by the 1536-B hipMemsetAsync before each launch.
static __device__ __forceinline__ void grid_sync(unsigned* base, int bx) {
    __syncthreads();
    if (threadIdx.x == 0) {
        __builtin_amdgcn_fence(__ATOMIC_RELEASE, "agent");
        __hip_atomic_fetch_add(base + (bx & 3) * 16, 1u,
                               __ATOMIC_RELAXED, __HIP_MEMORY_SCOPE_AGENT);
        if (bx == 0) {
            unsigned s;
            do {
                __builtin_amdgcn_s_sleep(1);
                s  = __hip_atomic_load(base +  0, __ATOMIC_RELAXED, __HIP_MEMORY_SCOPE_AGENT);
                s += __hip_atomic_load(base + 16, __ATOMIC_RELAXED, __HIP_MEMORY_SCOPE_AGENT);
                s += __hip_atomic_load(base + 32, __ATOMIC_RELAXED, __HIP_MEMORY_SCOPE_AGENT);
                s += __hip_atomic_load(base + 48, __ATOMIC_RELAXED, __HIP_MEMORY_SCOPE_AGENT);
            } while (s < (unsigned)GRID);
            __builtin_amdgcn_fence(__ATOMIC_ACQ_REL, "agent");
            __hip_atomic_store(base + 64,      1u, __ATOMIC_RELAXED, __HIP_MEMORY_SCOPE_AGENT);
            __hip_atomic_store(base + 64 + 16, 1u, __ATOMIC_RELAXED, __HIP_MEMORY_SCOPE_AGENT);
            __hip_atomic_store(base + 64 + 32, 1u, __ATOMIC_RELAXED, __HIP_MEMORY_SCOPE_AGENT);
            __hip_atomic_store(base + 64 + 48, 1u, __ATOMIC_RELAXED, __HIP_MEMORY_SCOPE_AGENT);
        } else {
            unsigned* fl = base + 64 + (bx & 3) * 16;
            while (__hip_atomic_load(fl, __ATOMIC_RELAXED, __HIP_MEMORY_SCOPE_AGENT) == 0u)
                __builtin_amdgcn_s_sleep(8);
        }
        __builtin_amdgcn_fence(__ATOMIC_ACQUIRE, "agent");
    }
    __syncthreads();
}

__global__ __launch_bounds__(256, 4) void fused_kernel(
    const float* __restrict__ inputs, const float* __restrict__ W1,
    const float* __restrict__ b1, const float* __restrict__ g1,
    const float* __restrict__ be1, const float* __restrict__ W2,
    const float* __restrict__ b2, const float* __restrict__ W3,
    const float* __restrict__ b3, const float* __restrict__ Wf1,
    const float* __restrict__ bf1, const float* __restrict__ gf,
    const float* __restrict__ bef, const float* __restrict__ Wf2,
    const float* __restrict__ bf2,
    float* __restrict__ AT, float* __restrict__ BT,
    unsigned short* __restrict__ ATh, unsigned short* __restrict__ BTh,
    float* __restrict__ SQp, float* __restrict__ statA, float* __restrict__ statB,
    float* __restrict__ f, float* __restrict__ fpartA, float* __restrict__ fpartB,
    unsigned short* __restrict__ W2p, unsigned short* __restrict__ W3p,
    float* __restrict__ edges_out, float* __restrict__ outp,
    unsigned* __restrict__ sync)
{
    // phase-union scratch: proj needs 10368 B (max), edges 9216, stats 4096, out 2688
    __shared__ __align__(16) char smem[10368];
    int tid = threadIdx.x;
    int bx = blockIdx.x;
    int lane = tid & 63, w = tid >> 6;

    // ================= Phase 1: proj + per-node partial sums + pack + zero ===
    if (bx < 512) {
        float* Xs  = (float*)smem;           // 16*33
        float* W1s = (float*)smem + 528;     // 2048
        float* red = (float*)smem + 2576;    // 16
        int n = bx >> 2, q = bx & 3;

        for (int idx = tid; idx < 2048; idx += 256) W1s[idx] = W1[idx];
        for (int idx = tid; idx < 512; idx += 256) {
            int r = idx >> 5, d = idx & 31;
            Xs[r * 33 + d] = inputs[(size_t)(q * 16 + r) * 4096 + n * 32 + d];
        }
        __syncthreads();

        int j = tid & 31, rb = tid >> 5;
        float b1j = b1[j];
        float sa = 0.f, qa = 0.f, sb = 0.f, qb = 0.f;
        #pragma unroll
        for (int i = 0; i < 2; ++i) {
            int r = rb * 2 + i;
            int b = q * 16 + r;
            float a = b1j, c = 0.f;
            #pragma unroll
            for (int k = 0; k < 32; ++k) {
                float x = Xs[r * 33 + k];
                a += x * W1s[k * 32 + j];
                c += x * W1s[(32 + k) * 32 + j];
            }
            size_t off = ((size_t)n * 64 + b) * 32 + j;
            AT[off] = a;  BT[off] = c;
            ATh[off] = f2bf(a);  BTh[off] = f2bf(c);
            sa += a; qa += a * a; sb += c; qb += c * c;
        }
        #pragma unroll
        for (int d = 32; d > 0; d >>= 1) {
            sa += __shfl_down(sa, d, 64);
            qa += __shfl_down(qa, d, 64);
            sb += __shfl_down(sb, d, 64);
            qb += __shfl_down(qb, d, 64);
        }
        if (lane == 0) { red[w*4+0] = sa; red[w*4+1] = qa; red[w*4+2] = sb; red[w*4+3] = qb; }
        __syncthreads();
        if (tid == 0) {
            float4 v;
            v.x = red[0] + red[4] + red[8]  + red[12];
            v.y = red[1] + red[5] + red[9]  + red[13];
            v.z = red[2] + red[6] + red[10] + red[14];
            v.w = red[3] + red[7] + red[11] + red[15];
            ((float4*)SQp)[n * 4 + q] = v;
        }
    } else if (bx == 512) {
        if (tid < 64) {      // pack W2/W3 -> bf16 B-frag layout
            int l = tid, nn2 = l & 15, kc = l >> 4;
            #pragma unroll
            for (int ct = 0; ct < 2; ++ct)
                #pragma unroll
                for (int jj = 0; jj < 8; ++jj) {
                    int k = kc * 8 + jj;
                    W2p[(ct * 64 + l) * 8 + jj] = f2bf(W2[k * 32 + ct * 16 + nn2]);
                }
            #pragma unroll
            for (int ct = 0; ct < 3; ++ct)
                #pragma unroll
                for (int jj = 0; jj < 8; ++jj) {
                    int k = kc * 8 + jj;
                    int c2 = ct * 16 + nn2;
                    W3p[(ct * 64 + l) * 8 + jj] = f2bf(c2 < 33 ? W3[k * 33 + c2] : 0.f);
                }
        }
    } else if (bx == 513) {
        for (int idx = tid; idx < 1024; idx += 256) {
            fpartA[idx] = 0.f;
            fpartB[idx] = 0.f;
        }
    }

    grid_sync(sync + 0, bx);

    // ================= Phase 2: LN stats via bf16 MFMA cross-GEMM ===========
    if (bx < 64) {
        float* part = (float*)smem;          // 4*64*4 floats
        int s0 = (bx >> 3) * 16, t0 = (bx & 7) * 16;
        int m = lane & 15, kc = lane >> 4;
        const unsigned short* abase = ATh + (size_t)(s0 + m) * 2048 + kc * 8 + w * 512;
        const unsigned short* bbase = BTh + (size_t)(t0 + m) * 2048 + kc * 8 + w * 512;

        f32x4 acc0 = {0.f, 0.f, 0.f, 0.f}, acc1 = {0.f, 0.f, 0.f, 0.f};
        #pragma unroll
        for (int step = 0; step < 8; ++step) {
            bf16x8 av0 = *(const bf16x8*)(abase + (2 * step) * 32);
            bf16x8 bv0 = *(const bf16x8*)(bbase + (2 * step) * 32);
            acc0 = __builtin_amdgcn_mfma_f32_16x16x32_bf16(av0, bv0, acc0, 0, 0, 0);
            bf16x8 av1 = *(const bf16x8*)(abase + (2 * step + 1) * 32);
            bf16x8 bv1 = *(const bf16x8*)(bbase + (2 * step + 1) * 32);
            acc1 = __builtin_amdgcn_mfma_f32_16x16x32_bf16(av1, bv1, acc1, 0, 0, 0);
        }
        f32x4 acc;
        acc[0] = acc0[0] + acc1[0]; acc[1] = acc0[1] + acc1[1];
        acc[2] = acc0[2] + acc1[2]; acc[3] = acc0[3] + acc1[3];
        *(f32x4*)&part[(w * 64 + lane) * 4] = acc;
        __syncthreads();

        if (w == 0) {
            #pragma unroll
            for (int ww = 1; ww < 4; ++ww) {
                f32x4 o2 = *(const f32x4*)&part[(ww * 64 + lane) * 4];
                acc[0] += o2[0]; acc[1] += o2[1]; acc[2] += o2[2]; acc[3] += o2[3];
            }
            int col = lane & 15, quad = lane >> 4;
            int t = t0 + col;
            float sbt = 0.f, qbt = 0.f;
            #pragma unroll
            for (int o2 = 0; o2 < 4; ++o2) {
                float4 v = ((const float4*)SQp)[t * 4 + o2];
                sbt += v.z; qbt += v.w;
            }
            #pragma unroll
            for (int r = 0; r < 4; ++r) {
                int s = s0 + quad * 4 + r;
                if (s != t) {
                    float sas = 0.f, qas = 0.f;
                    #pragma unroll
                    for (int o2 = 0; o2 < 4; ++o2) {
                        float4 v = ((const float4*)SQp)[s * 4 + o2];
                        sas += v.x; qas += v.y;
                    }
                    int e = t - (t > s);
                    int p = s * 127 + e;
                    float S = sas + sbt;
                    float Q = qas + qbt + 2.f * acc[r];
                    float mean = S * (1.f / 2048.f);
                    float var  = Q * (1.f / 2048.f) - mean * mean;
                    float inv  = rsqrtf(var + EPSF);
                    float sc   = inv * g1[p];
                    statA[p] = sc;
                    statB[p] = be1[p] - mean * sc;
                }
            }
        }
    }

    grid_sync(sync + 128, bx);

    // ================= Phase 3: edge MLP, 8 virtual blocks per real block ===
    {
        unsigned short (*Hs)[512] = (unsigned short (*)[512])smem;   // 4096 B
        float* Wf1s = (float*)(smem + 4096);                         // 4096 B
        float (*aggbuf)[4][32] = (float (*)[4][32])(smem + 8192);    // 1024 B

        int m = lane & 15;          // A-frag row within tile / C-frag col
        int kb = lane >> 4;         // k-block (8 wide)
        int col = m;
        int q4 = kb * 4;            // C-frag row group
        int qbase = lane & 48;

        for (int idx = tid; idx < 1024; idx += 256) Wf1s[idx] = Wf1[idx];

        bf16x8 wb2[2], wb3[3];
        wb2[0] = *(const bf16x8*)(W2p + (0 * 64 + lane) * 8);
        wb2[1] = *(const bf16x8*)(W2p + (1 * 64 + lane) * 8);
        wb3[0] = *(const bf16x8*)(W3p + (0 * 64 + lane) * 8);
        wb3[1] = *(const bf16x8*)(W3p + (1 * 64 + lane) * 8);
        wb3[2] = *(const bf16x8*)(W3p + (2 * 64 + lane) * 8);
        float b2c0 = b2[col], b2c1 = b2[16 + col];
        float b3c[3];
        #pragma unroll
        for (int ct = 0; ct < 3; ++ct) {
            int c = ct * 16 + col;
            b3c[ct] = (c < 33) ? b3[c] : 0.f;
        }

        int bb2 = bx >> 4;
        int sbase = (bx & 15) * 8;

        for (int vi = 0; vi < 8; ++vi) {
            int s = sbase + vi;
            const float4* asl = (const float4*)(AT + ((size_t)s * 64 + bb2) * 32 + kb * 8);
            float4 a0 = asl[0], a1 = asl[1];
            f32x2 av[4];
            av[0][0]=a0.x; av[0][1]=a0.y; av[1][0]=a0.z; av[1][1]=a0.w;
            av[2][0]=a1.x; av[2][1]=a1.y; av[3][0]=a1.z; av[3][1]=a1.w;

            float aggpart[3] = {0.f, 0.f, 0.f};

            #pragma unroll
            for (int rt = 0; rt < 2; ++rt) {
                int tile = w * 2 + rt;
                int e = tile * 16 + m;
                bool valid = (e < 127);
                int ee = valid ? e : 0;
                int t = ee + (ee >= s);
                int p = s * 127 + ee;
                // invalid lanes: zero scale/shift -> nh == 0 (replaces 8 cndmasks)
                float sc = valid ? statA[p] : 0.f;
                float sh = valid ? statB[p] : 0.f;
                f32x2 sc2; sc2[0] = sc; sc2[1] = sc;
                f32x2 sh2; sh2[0] = sh; sh2[1] = sh;

                const float4* bsl = (const float4*)(BT + ((size_t)t * 64 + bb2) * 32 + kb * 8);
                float4 bv0 = bsl[0], bv1 = bsl[1];
                f32x2 bv[4];
                bv[0][0]=bv0.x; bv[0][1]=bv0.y; bv[1][0]=bv0.z; bv[1][1]=bv0.w;
                bv[2][0]=bv1.x; bv[2][1]=bv1.y; bv[3][0]=bv1.z; bv[3][1]=bv1.w;

                // LN-apply + leaky on packed f32 pairs (v_pk_add/v_pk_fma path)
                union { bf16x8 v; unsigned u[4]; } AF;
                #pragma unroll
                for (int i = 0; i < 4; ++i) {
                    f32x2 y = (av[i] + bv[i]) * sc2 + sh2;
                    f32x2 tq = y * 0.01f;
                    float n0 = fmaxf(y[0], tq[0]);
                    float n1 = fmaxf(y[1], tq[1]);
                    AF.u[i] = pk2bf(n0, n1);
                }

                // GEMM2
                f32x4 c0 = {0.f, 0.f, 0.f, 0.f}, c1 = {0.f, 0.f, 0.f, 0.f};
                c0 = __builtin_amdgcn_mfma_f32_16x16x32_bf16(AF.v, wb2[0], c0, 0, 0, 0);
                c1 = __builtin_amdgcn_mfma_f32_16x16x32_bf16(AF.v, wb2[1], c1, 0, 0, 0);

                // C -> A transpose via wave-private swizzled scratch (no barrier)
                #pragma unroll
                for (int reg = 0; reg < 4; ++reg) {
                    int row = q4 + reg;
                    float x = leakyf(c0[reg] + b2c0);
                    float y = leakyf(c1[reg] + b2c1);
                    int cA = col;
                    int cB = col + 16;
                    Hs[w][row * 32 + (((cA >> 3) ^ (row >> 2)) & 3) * 8 + (cA & 7)] = f2bf(x);
                    Hs[w][row * 32 + (((cB >> 3) ^ (row >> 2)) & 3) * 8 + (cB & 7)] = f2bf(y);
                }
                bf16x8 a2 = *(const bf16x8*)&Hs[w][m * 32 + ((kb ^ (m >> 2)) & 3) * 8];

                // GEMM3
                f32x4 oo[3];
                #pragma unroll
                for (int ct = 0; ct < 3; ++ct) {
                    f32x4 cc = {0.f, 0.f, 0.f, 0.f};
                    oo[ct] = __builtin_amdgcn_mfma_f32_16x16x32_bf16(a2, wb3[ct], cc, 0, 0, 0);
                }

                float v0 = 0.f, v1 = 0.f, v2 = 0.f, v3 = 0.f;
                int grow0 = tile * 16 + q4;
                if (col == 0) {
                    v0 = 1.f / (1.f + __expf(-(oo[0][0] + b3c[0])));
                    v1 = 1.f / (1.f + __expf(-(oo[0][1] + b3c[0])));
                    v2 = 1.f / (1.f + __expf(-(oo[0][2] + b3c[0])));
                    v3 = (grow0 == 124) ? 0.f
                       : 1.f / (1.f + __expf(-(oo[0][3] + b3c[0])));
                    float* ep = edges_out + (size_t)bb2 * PP + s * 127 + grow0;
                    ep[0] = v0; ep[1] = v1; ep[2] = v2;
                    if (grow0 != 124) ep[3] = v3;
                }
                float ev0 = __shfl(v0, qbase, 64);
                float ev1 = __shfl(v1, qbase, 64);
                float ev2 = __shfl(v2, qbase, 64);
                float ev3 = __shfl(v3, qbase, 64);

                #pragma unroll
                for (int ct = 0; ct < 3; ++ct) {
                    float bb3 = b3c[ct];
                    float pt = ev0 * (oo[ct][0] + bb3) + ev1 * (oo[ct][1] + bb3)
                             + ev2 * (oo[ct][2] + bb3) + ev3 * (oo[ct][3] + bb3);
                    aggpart[ct] += pt;
                }
            }

            int par = vi & 1;
            #pragma unroll
            for (int ct = 0; ct < 3; ++ct) {
                float pt = aggpart[ct];
                pt += __shfl_xor(pt, 16, 64);
                pt += __shfl_xor(pt, 32, 64);
                int c = ct * 16 + col;
                if (kb == 0 && c >= 1 && c <= 32) aggbuf[par][w][c - 1] = pt;
            }
            __syncthreads();    // one barrier per vi (parity keeps vi+1 writes safe)

            // f-row tail: rotate the working wave so tails balance across waves
            if (w == (vi & 3) && lane < 16) {
                int j = lane;
                size_t row = (size_t)bb2 * 128 + s;
                const float* xrow = inputs + row * 32;
                float acc = bf1[j];
                #pragma unroll
                for (int k = 0; k < 32; ++k) acc += xrow[k] * Wf1s[k * 16 + j];
                #pragma unroll
                for (int k = 0; k < 32; ++k) {
                    float tot = aggbuf[par][0][k] + aggbuf[par][1][k]
                              + aggbuf[par][2][k] + aggbuf[par][3][k];
                    acc += tot * Wf1s[(32 + k) * 16 + j];
                }
                f[row * 16 + j] = acc;
                int bucket = s & 63;
                atomicAdd(&fpartA[bucket * 16 + j], acc);
                atomicAdd(&fpartB[bucket * 16 + j], acc * acc);
            }
        }
    }

    grid_sync(sync + 256, bx);

    // ================= Phase 4: f-stats reduce (redundant) + out =============
    {
        float* Wf2s = (float*)smem;              // 512
        float* scv  = (float*)smem + 512;        // 16
        float* shv  = (float*)smem + 528;        // 16
        float* fs   = (float*)smem + 544;        // 128

        for (int idx = tid; idx < 512; idx += 256) Wf2s[idx] = Wf2[idx];
        if (tid < 16) {
            float S = 0.f, Q = 0.f;
            #pragma unroll
            for (int g = 0; g < 64; ++g) {
                S += fpartA[g * 16 + tid];
                Q += fpartB[g * 16 + tid];
            }
            float mean = S * (1.f / 8192.f);
            float var  = Q * (1.f / 8192.f) - mean * mean;
            float inv  = rsqrtf(var + EPSF);
            float s2   = inv * gf[tid];
            scv[tid] = s2;
            shv[tid] = bef[tid] - mean * s2;
        }
        int row0 = bx * 8;
        if (tid < 128) {
            int r = tid >> 4, j = tid & 15;
            fs[r * 16 + j] = f[(size_t)(row0 + r) * 16 + j];
        }
        __syncthreads();

        int rl = tid >> 5, d = tid & 31;
        float acc = bf2[d];
        #pragma unroll
        for (int j2 = 0; j2 < 16; ++j2) {
            float v = fs[rl * 16 + j2] * scv[j2] + shv[j2];
            v = leakyf(v);
            acc += v * Wf2s[j2 * 32 + d];
        }
        outp[(size_t)(row0 + rl) * 32 + d] = acc;
    }
}

extern "C" void kernel_launch(void* const* d_in, const int* in_sizes, int n_in,
                              void* d_out, int out_size, void* d_ws, size_t ws_size,
                              hipStream_t stream) {
    const float* inputs = (const float*)d_in[0];
    const float* W1   = (const float*)d_in[3];
    const float* b1   = (const float*)d_in[4];
    const float* g1   = (const float*)d_in[5];
    const float* be1  = (const float*)d_in[6];
    const float* W2   = (const float*)d_in[7];
    const float* b2   = (const float*)d_in[8];
    const float* W3   = (const float*)d_in[9];
    const float* b3   = (const float*)d_in[10];
    const float* Wf1  = (const float*)d_in[11];
    const float* bf1  = (const float*)d_in[12];
    const float* gf   = (const float*)d_in[13];
    const float* bef  = (const float*)d_in[14];
    const float* Wf2  = (const float*)d_in[15];
    const float* bf2  = (const float*)d_in[16];

    float* ws = (float*)d_ws;
    float* AT     = ws;                              // 262144
    float* BT     = ws + 262144;                     // 262144
    unsigned short* ATh = (unsigned short*)(ws + 524288);  // 262144 ush
    unsigned short* BTh = ATh + 262144;                    // 262144 ush
    float* SQp    = ws + 786432;                     // 2048 slot (2044 used)
    float* statA  = ws + 790528;                     // 16256
    float* statB  = ws + 806784;                     // 16256
    float* f      = ws + 823040;                     // 131072
    float* fpartA = ws + 954112;                     // 1024
    float* fpartB = ws + 955136;                     // 1024
    unsigned short* W2p = (unsigned short*)(ws + 956160);  // 1024 ush
    unsigned short* W3p = W2p + 1024;                      // 1536 ush
    // barrier state in SQp slack (floats 788480..790527 unused): 3 x 128 dwords
    unsigned* sync = (unsigned*)(ws + 788480);

    float* edges_out = (float*)d_out;                    // B*P
    float* outp      = edges_out + (size_t)BB * PP;      // B*N*D

    hipMemsetAsync(sync, 0, 1536, stream);
    fused_kernel<<<GRID, 256, 0, stream>>>(
        inputs, W1, b1, g1, be1, W2, b2, W3, b3, Wf1, bf1, gf, bef, Wf2, bf2,
        AT, BT, ATh, BTh, SQp, statA, statB, f, fpartA, fpartB, W2p, W3p,
        edges_out, outp, sync);
}

// Round 4
// 146.203 us; speedup vs baseline: 3.0118x; 1.4293x over previous
//
#include <hip/hip_runtime.h>
#include <hip/hip_bf16.h>
#include <math.h>

#define BB 64
#define NN 128
#define DD 32
#define PP (NN * (NN - 1))   // 16256
#define EPSF 1e-5f

typedef __attribute__((ext_vector_type(8))) short bf16x8;
typedef __attribute__((ext_vector_type(4))) float f32x4;
typedef __attribute__((ext_vector_type(2))) float f32x2;

static __device__ __forceinline__ unsigned pk2bf(float a, float b) {
    float2 t; t.x = a; t.y = b;
    __hip_bfloat162 h = __float22bfloat162_rn(t);   // v_cvt_pk_bf16_f32
    unsigned u;
    __builtin_memcpy(&u, &h, 4);
    return u;
}
// single-instruction RNE f32->bf16 via the packed builtin (low half);
// no inline asm (guide m240: hand-written cvt_pk asm regressed).
static __device__ __forceinline__ unsigned short f2bf(float x) {
    return (unsigned short)pk2bf(x, x);
}
static __device__ __forceinline__ float leakyf(float x) {
    return fmaxf(x, 0.01f * x);
}

// ============ Kernel 1: proj + per-node partial sums + pack + zero ============
// 512 blocks: n = bx>>2, b-quarter q = bx&3 (16 rows). 256 thr.
__global__ __launch_bounds__(256) void proj_kernel(
    const float* __restrict__ inputs, const float* __restrict__ W1,
    const float* __restrict__ b1,
    const float* __restrict__ W2, const float* __restrict__ W3,
    float* __restrict__ AT, float* __restrict__ BT,
    unsigned short* __restrict__ ATh, unsigned short* __restrict__ BTh,
    float* __restrict__ SQp,
    unsigned short* __restrict__ W2p, unsigned short* __restrict__ W3p,
    float* __restrict__ fpartA, float* __restrict__ fpartB)
{
    __shared__ float Xs[16 * 33];
    __shared__ float W1s[2048];
    __shared__ float red[16];

    int tid = threadIdx.x;
    int n = blockIdx.x >> 2, q = blockIdx.x & 3;

    for (int idx = tid; idx < 2048; idx += 256) W1s[idx] = W1[idx];
    for (int idx = tid; idx < 512; idx += 256) {
        int r = idx >> 5, d = idx & 31;
        Xs[r * 33 + d] = inputs[(q * 16 + r) * 4096 + n * 32 + d];
    }
    __syncthreads();

    int j = tid & 31, rb = tid >> 5;
    int lane = tid & 63, w = tid >> 6;
    float b1j = b1[j];
    float sa = 0.f, qa = 0.f, sb = 0.f, qb = 0.f;
    #pragma unroll
    for (int i = 0; i < 2; ++i) {
        int r = rb * 2 + i;
        int b = q * 16 + r;
        float a = b1j, c = 0.f;
        #pragma unroll
        for (int k = 0; k < 32; ++k) {
            float x = Xs[r * 33 + k];
            a += x * W1s[k * 32 + j];
            c += x * W1s[(32 + k) * 32 + j];
        }
        int off = (n * 64 + b) * 32 + j;
        AT[off] = a;  BT[off] = c;
        ATh[off] = f2bf(a);  BTh[off] = f2bf(c);
        sa += a; qa += a * a; sb += c; qb += c * c;
    }
    #pragma unroll
    for (int d = 32; d > 0; d >>= 1) {
        sa += __shfl_down(sa, d, 64);
        qa += __shfl_down(qa, d, 64);
        sb += __shfl_down(sb, d, 64);
        qb += __shfl_down(qb, d, 64);
    }
    if (lane == 0) { red[w*4+0] = sa; red[w*4+1] = qa; red[w*4+2] = sb; red[w*4+3] = qb; }
    __syncthreads();
    if (tid == 0) {
        float4 v;
        v.x = red[0] + red[4] + red[8]  + red[12];
        v.y = red[1] + red[5] + red[9]  + red[13];
        v.z = red[2] + red[6] + red[10] + red[14];
        v.w = red[3] + red[7] + red[11] + red[15];
        ((float4*)SQp)[n * 4 + q] = v;
    }

    if (blockIdx.x == 0 && tid < 64) {      // pack W2/W3 -> bf16 B-frag layout
        int l = tid, nn2 = l & 15, kc = l >> 4;
        #pragma unroll
        for (int ct = 0; ct < 2; ++ct)
            #pragma unroll
            for (int jj = 0; jj < 8; ++jj) {
                int k = kc * 8 + jj;
                W2p[(ct * 64 + l) * 8 + jj] = f2bf(W2[k * 32 + ct * 16 + nn2]);
            }
        #pragma unroll
        for (int ct = 0; ct < 3; ++ct)
            #pragma unroll
            for (int jj = 0; jj < 8; ++jj) {
                int k = kc * 8 + jj;
                int c2 = ct * 16 + nn2;
                W3p[(ct * 64 + l) * 8 + jj] = f2bf(c2 < 33 ? W3[k * 33 + c2] : 0.f);
            }
    }
    if (blockIdx.x == 1) {
        for (int idx = tid; idx < 1024; idx += 256) {
            fpartA[idx] = 0.f;
            fpartB[idx] = 0.f;
        }
    }
}

// ============ Kernel 2: LN stats via bf16 MFMA cross-GEMM ============
// 64 blocks: 16x16 (s,t) tile; 4 waves split K=2048; dual accumulators.
// Writes interleaved statAB[p] = {scale, shift} (float2) for a single
// dwordx2 load in edges_kernel.
__global__ __launch_bounds__(256) void stats2_kernel(
    const unsigned short* __restrict__ ATh, const unsigned short* __restrict__ BTh,
    const float* __restrict__ SQp,
    const float* __restrict__ g1, const float* __restrict__ be1,
    float* __restrict__ statAB)
{
    __shared__ __align__(16) float part[4 * 64 * 4];
    int tid = threadIdx.x;
    int lane = tid & 63, w = tid >> 6;
    int s0 = (blockIdx.x >> 3) * 16, t0 = (blockIdx.x & 7) * 16;

    int m = lane & 15, kc = lane >> 4;
    const unsigned short* abase = ATh + (s0 + m) * 2048 + kc * 8 + w * 512;
    const unsigned short* bbase = BTh + (t0 + m) * 2048 + kc * 8 + w * 512;

    f32x4 acc0 = {0.f, 0.f, 0.f, 0.f}, acc1 = {0.f, 0.f, 0.f, 0.f};
    #pragma unroll
    for (int step = 0; step < 8; ++step) {
        bf16x8 av0 = *(const bf16x8*)(abase + (2 * step) * 32);
        bf16x8 bv0 = *(const bf16x8*)(bbase + (2 * step) * 32);
        acc0 = __builtin_amdgcn_mfma_f32_16x16x32_bf16(av0, bv0, acc0, 0, 0, 0);
        bf16x8 av1 = *(const bf16x8*)(abase + (2 * step + 1) * 32);
        bf16x8 bv1 = *(const bf16x8*)(bbase + (2 * step + 1) * 32);
        acc1 = __builtin_amdgcn_mfma_f32_16x16x32_bf16(av1, bv1, acc1, 0, 0, 0);
    }
    f32x4 acc;
    acc[0] = acc0[0] + acc1[0]; acc[1] = acc0[1] + acc1[1];
    acc[2] = acc0[2] + acc1[2]; acc[3] = acc0[3] + acc1[3];
    *(f32x4*)&part[(w * 64 + lane) * 4] = acc;
    __syncthreads();

    if (w == 0) {
        #pragma unroll
        for (int ww = 1; ww < 4; ++ww) {
            f32x4 o2 = *(const f32x4*)&part[(ww * 64 + lane) * 4];
            acc[0] += o2[0]; acc[1] += o2[1]; acc[2] += o2[2]; acc[3] += o2[3];
        }
        int col = lane & 15, quad = lane >> 4;
        int t = t0 + col;
        float sbt = 0.f, qbt = 0.f;
        #pragma unroll
        for (int o2 = 0; o2 < 4; ++o2) {
            float4 v = ((const float4*)SQp)[t * 4 + o2];
            sbt += v.z; qbt += v.w;
        }
        #pragma unroll
        for (int r = 0; r < 4; ++r) {
            int s = s0 + quad * 4 + r;
            if (s != t) {
                float sas = 0.f, qas = 0.f;
                #pragma unroll
                for (int o2 = 0; o2 < 4; ++o2) {
                    float4 v = ((const float4*)SQp)[s * 4 + o2];
                    sas += v.x; qas += v.y;
                }
                int e = t - (t > s);
                int p = s * 127 + e;
                float S = sas + sbt;
                float Q = qas + qbt + 2.f * acc[r];
                float mean = S * (1.f / 2048.f);
                float var  = Q * (1.f / 2048.f) - mean * mean;
                float inv  = rsqrtf(var + EPSF);
                float sc   = inv * g1[p];
                float2 o;
                o.x = sc;
                o.y = be1[p] - mean * sc;
                ((float2*)statAB)[p] = o;
            }
        }
    }
}

// ============ Kernel 3: edge MLP, wave-private pipeline, ONE barrier =========
// 8192 blocks: s = bx&127, b = bx>>7. 4 waves x 2 row-tiles of 16 edges.
// __launch_bounds__(256, 8): 48 VGPR fits the 64-reg/8-wave budget ->
// 8 blocks/CU co-resident (round-0 occupancy was 39%).
__global__ __launch_bounds__(256, 8) void edges_kernel(
    const float* __restrict__ AT, const float* __restrict__ BT,
    const float* __restrict__ statAB,
    const unsigned short* __restrict__ W2p, const unsigned short* __restrict__ W3p,
    const float* __restrict__ b2, const float* __restrict__ b3,
    const float* __restrict__ inputs, const float* __restrict__ Wf1,
    const float* __restrict__ bf1,
    float* __restrict__ edges_out,
    float* __restrict__ f, float* __restrict__ fpartA, float* __restrict__ fpartB)
{
    __shared__ __align__(16) unsigned short Hs[4][512];   // per-wave 16x32 swizzled
    __shared__ float Wf1s[1024];
    __shared__ float aggbuf[4][32];

    int tid = threadIdx.x;
    int s = blockIdx.x & 127;
    int b = blockIdx.x >> 7;
    int lane = tid & 63, w = tid >> 6;
    int m = lane & 15;          // A-frag row within tile / C-frag col
    int kb = lane >> 4;         // k-block (8 wide)
    int col = m;
    int q4 = kb * 4;            // C-frag row group
    int qbase = lane & 48;

    for (int idx = tid; idx < 1024; idx += 256) Wf1s[idx] = Wf1[idx];

    // B fragments + biases (block-invariant)
    bf16x8 wb2[2], wb3[3];
    wb2[0] = *(const bf16x8*)(W2p + (0 * 64 + lane) * 8);
    wb2[1] = *(const bf16x8*)(W2p + (1 * 64 + lane) * 8);
    wb3[0] = *(const bf16x8*)(W3p + (0 * 64 + lane) * 8);
    wb3[1] = *(const bf16x8*)(W3p + (1 * 64 + lane) * 8);
    wb3[2] = *(const bf16x8*)(W3p + (2 * 64 + lane) * 8);
    float b2c0 = b2[col], b2c1 = b2[16 + col];
    float b3c[3];
    #pragma unroll
    for (int ct = 0; ct < 3; ++ct) {
        int c = ct * 16 + col;
        b3c[ct] = (c < 33) ? b3[c] : 0.f;
    }

    // lane's AT slice (same for both tiles); 32-bit offsets throughout
    const float4* asl = (const float4*)(AT + (s * 64 + b) * 32 + kb * 8);
    float4 a0 = asl[0], a1 = asl[1];
    f32x2 av[4];
    av[0][0]=a0.x; av[0][1]=a0.y; av[1][0]=a0.z; av[1][1]=a0.w;
    av[2][0]=a1.x; av[2][1]=a1.y; av[3][0]=a1.z; av[3][1]=a1.w;

    float aggpart[3] = {0.f, 0.f, 0.f};

    #pragma unroll
    for (int rt = 0; rt < 2; ++rt) {
        int tile = w * 2 + rt;
        int e = tile * 16 + m;
        bool valid = (e < 127);
        int ee = valid ? e : 0;
        int t = ee + (ee >= s);
        int p = s * 127 + ee;
        float2 st = ((const float2*)statAB)[p];
        // invalid lanes: zero scale/shift -> nh == 0 (2 cndmasks, no per-elem mask)
        float sc = valid ? st.x : 0.f;
        float sh = valid ? st.y : 0.f;
        f32x2 sc2; sc2[0] = sc; sc2[1] = sc;
        f32x2 sh2; sh2[0] = sh; sh2[1] = sh;

        const float4* bsl = (const float4*)(BT + (t * 64 + b) * 32 + kb * 8);
        float4 bv0 = bsl[0], bv1 = bsl[1];
        f32x2 bv[4];
        bv[0][0]=bv0.x; bv[0][1]=bv0.y; bv[1][0]=bv0.z; bv[1][1]=bv0.w;
        bv[2][0]=bv1.x; bv[2][1]=bv1.y; bv[3][0]=bv1.z; bv[3][1]=bv1.w;

        // LN-apply + leaky on packed f32 pairs (v_pk_add/v_pk_fma path)
        union { bf16x8 v; unsigned u[4]; } AF;
        #pragma unroll
        for (int i = 0; i < 4; ++i) {
            f32x2 y = (av[i] + bv[i]) * sc2 + sh2;
            f32x2 tq = y * 0.01f;
            float n0 = fmaxf(y[0], tq[0]);
            float n1 = fmaxf(y[1], tq[1]);
            AF.u[i] = pk2bf(n0, n1);
        }

        // GEMM2: h2 tile (C layout)
        f32x4 c0 = {0.f, 0.f, 0.f, 0.f}, c1 = {0.f, 0.f, 0.f, 0.f};
        c0 = __builtin_amdgcn_mfma_f32_16x16x32_bf16(AF.v, wb2[0], c0, 0, 0, 0);
        c1 = __builtin_amdgcn_mfma_f32_16x16x32_bf16(AF.v, wb2[1], c1, 0, 0, 0);

        // C -> A transpose via wave-private swizzled scratch (no barrier)
        #pragma unroll
        for (int reg = 0; reg < 4; ++reg) {
            int row = q4 + reg;
            float x = leakyf(c0[reg] + b2c0);
            float y = leakyf(c1[reg] + b2c1);
            int cA = col;            // < 16
            int cB = col + 16;
            Hs[w][row * 32 + (((cA >> 3) ^ (row >> 2)) & 3) * 8 + (cA & 7)] = f2bf(x);
            Hs[w][row * 32 + (((cB >> 3) ^ (row >> 2)) & 3) * 8 + (cB & 7)] = f2bf(y);
        }
        // wave-synchronous read-back (compiler emits lgkmcnt wait)
        bf16x8 a2 = *(const bf16x8*)&Hs[w][m * 32 + ((kb ^ (m >> 2)) & 3) * 8];

        // GEMM3
        f32x4 oo[3];
        #pragma unroll
        for (int ct = 0; ct < 3; ++ct) {
            f32x4 cc = {0.f, 0.f, 0.f, 0.f};
            oo[ct] = __builtin_amdgcn_mfma_f32_16x16x32_bf16(a2, wb3[ct], cc, 0, 0, 0);
        }

        // sigmoid on col 0 (lanes with col==0 hold rows q4+reg), then quad shfl
        float v0 = 0.f, v1 = 0.f, v2 = 0.f, v3 = 0.f;
        int grow0 = tile * 16 + q4;
        if (col == 0) {
            v0 = 1.f / (1.f + __expf(-(oo[0][0] + b3c[0])));
            v1 = 1.f / (1.f + __expf(-(oo[0][1] + b3c[0])));
            v2 = 1.f / (1.f + __expf(-(oo[0][2] + b3c[0])));
            v3 = (grow0 == 124) ? 0.f
               : 1.f / (1.f + __expf(-(oo[0][3] + b3c[0])));
            float* ep = edges_out + b * PP + s * 127 + grow0;
            ep[0] = v0; ep[1] = v1; ep[2] = v2;
            if (grow0 != 124) ep[3] = v3;
        }
        float ev0 = __shfl(v0, qbase, 64);
        float ev1 = __shfl(v1, qbase, 64);
        float ev2 = __shfl(v2, qbase, 64);
        float ev3 = __shfl(v3, qbase, 64);

        // agg partials (cols 1..32 of the 48-wide output)
        #pragma unroll
        for (int ct = 0; ct < 3; ++ct) {
            float bb3 = b3c[ct];
            float pt = ev0 * (oo[ct][0] + bb3) + ev1 * (oo[ct][1] + bb3)
                     + ev2 * (oo[ct][2] + bb3) + ev3 * (oo[ct][3] + bb3);
            aggpart[ct] += pt;
        }
    }

    // quad-reduce agg partials (sum over kb groups = rows), store wave slice
    #pragma unroll
    for (int ct = 0; ct < 3; ++ct) {
        float pt = aggpart[ct];
        pt += __shfl_xor(pt, 16, 64);
        pt += __shfl_xor(pt, 32, 64);
        int c = ct * 16 + col;
        if (kb == 0 && c >= 1 && c <= 32) aggbuf[w][c - 1] = pt;
    }
    __syncthreads();                                   // the ONLY barrier

    // f-row tail: all 64 lanes of wave 0 (4 k-groups x 16 j), 2-fold reduce
    if (w == 0) {
        int j = lane & 15, kg = lane >> 4;
        int row = b * 128 + s;
        const float* xrow = inputs + row * 32;
        float acc = 0.f;
        if (kg < 2) {
            #pragma unroll
            for (int i = 0; i < 16; ++i) {
                int k = kg * 16 + i;
                acc += xrow[k] * Wf1s[k * 16 + j];
            }
        } else {
            #pragma unroll
            for (int i = 0; i < 16; ++i) {
                int k = (kg - 2) * 16 + i;
                float tot = aggbuf[0][k] + aggbuf[1][k] + aggbuf[2][k] + aggbuf[3][k];
                acc += tot * Wf1s[(32 + k) * 16 + j];
            }
        }
        acc += __shfl_xor(acc, 16, 64);
        acc += __shfl_xor(acc, 32, 64);
        if (lane < 16) {
            acc += bf1[j];
            f[row * 16 + j] = acc;
            int bucket = blockIdx.x & 63;
            atomicAdd(&fpartA[bucket * 16 + j], acc);
            atomicAdd(&fpartB[bucket * 16 + j], acc * acc);
        }
    }
}

// ============ Kernel 4: f-stats reduce (redundant per block) + out ============
__global__ __launch_bounds__(256) void out_kernel(
    const float* __restrict__ f,
    const float* __restrict__ fpartA, const float* __restrict__ fpartB,
    const float* __restrict__ gf, const float* __restrict__ bef,
    const float* __restrict__ Wf2, const float* __restrict__ bf2,
    float* __restrict__ outp)
{
    __shared__ float Wf2s[512];
    __shared__ float sc[16], sh[16];
    __shared__ float fs[128];

    int tid = threadIdx.x;
    for (int idx = tid; idx < 512; idx += 256) Wf2s[idx] = Wf2[idx];
    if (tid < 16) {
        float S = 0.f, Q = 0.f;
        #pragma unroll
        for (int g = 0; g < 64; ++g) {
            S += fpartA[g * 16 + tid];
            Q += fpartB[g * 16 + tid];
        }
        float mean = S * (1.f / 8192.f);
        float var  = Q * (1.f / 8192.f) - mean * mean;
        float inv  = rsqrtf(var + EPSF);
        float s2   = inv * gf[tid];
        sc[tid] = s2;
        sh[tid] = bef[tid] - mean * s2;
    }
    int row0 = blockIdx.x * 8;
    if (tid < 128) {
        int r = tid >> 4, j = tid & 15;
        fs[r * 16 + j] = f[(row0 + r) * 16 + j];
    }
    __syncthreads();

    int rl = tid >> 5, d = tid & 31;
    float acc = bf2[d];
    #pragma unroll
    for (int j = 0; j < 16; ++j) {
        float v = fs[rl * 16 + j] * sc[j] + sh[j];
        v = leakyf(v);
        acc += v * Wf2s[j * 32 + d];
    }
    outp[(row0 + rl) * 32 + d] = acc;
}

extern "C" void kernel_launch(void* const* d_in, const int* in_sizes, int n_in,
                              void* d_out, int out_size, void* d_ws, size_t ws_size,
                              hipStream_t stream) {
    const float* inputs = (const float*)d_in[0];
    const float* W1   = (const float*)d_in[3];
    const float* b1   = (const float*)d_in[4];
    const float* g1   = (const float*)d_in[5];
    const float* be1  = (const float*)d_in[6];
    const float* W2   = (const float*)d_in[7];
    const float* b2   = (const float*)d_in[8];
    const float* W3   = (const float*)d_in[9];
    const float* b3   = (const float*)d_in[10];
    const float* Wf1  = (const float*)d_in[11];
    const float* bf1  = (const float*)d_in[12];
    const float* gf   = (const float*)d_in[13];
    const float* bef  = (const float*)d_in[14];
    const float* Wf2  = (const float*)d_in[15];
    const float* bf2  = (const float*)d_in[16];

    float* ws = (float*)d_ws;
    float* AT     = ws;                              // 262144
    float* BT     = ws + 262144;                     // 262144
    unsigned short* ATh = (unsigned short*)(ws + 524288);  // 262144 ush
    unsigned short* BTh = ATh + 262144;                    // 262144 ush
    float* SQp    = ws + 786432;                     // 2048 (128 n x 4 q x float4)
    float* statAB = ws + 790528;                     // 32512 (P x float2, interleaved)
    float* f      = ws + 823040;                     // 131072
    float* fpartA = ws + 954112;                     // 1024
    float* fpartB = ws + 955136;                     // 1024
    unsigned short* W2p = (unsigned short*)(ws + 956160);  // 1024 ush
    unsigned short* W3p = W2p + 1024;                      // 1536 ush

    float* edges_out = (float*)d_out;                    // B*P
    float* outp      = edges_out + (size_t)BB * PP;      // B*N*D

    proj_kernel<<<512, 256, 0, stream>>>(inputs, W1, b1, W2, W3,
                                         AT, BT, ATh, BTh, SQp,
                                         W2p, W3p, fpartA, fpartB);
    stats2_kernel<<<64, 256, 0, stream>>>(ATh, BTh, SQp, g1, be1, statAB);
    edges_kernel<<<8192, 256, 0, stream>>>(AT, BT, statAB, W2p, W3p,
                                           b2, b3, inputs, Wf1, bf1,
                                           edges_out, f, fpartA, fpartB);
    out_kernel<<<1024, 256, 0, stream>>>(f, fpartA, fpartB, gf, bef, Wf2, bf2, outp);
}

// Round 5
// 138.467 us; speedup vs baseline: 3.1801x; 1.0559x over previous
//
#include <hip/hip_runtime.h>
#include <hip/hip_bf16.h>
#include <math.h>

#define BB 64
#define NN 128
#define DD 32
#define PP (NN * (NN - 1))   // 16256
#define EPSF 1e-5f

typedef __attribute__((ext_vector_type(8))) short bf16x8;
typedef __attribute__((ext_vector_type(4))) float f32x4;
typedef __attribute__((ext_vector_type(2))) float f32x2;

static __device__ __forceinline__ unsigned pk2bf(float a, float b) {
    float2 t; t.x = a; t.y = b;
    __hip_bfloat162 h = __float22bfloat162_rn(t);   // v_cvt_pk_bf16_f32
    unsigned u;
    __builtin_memcpy(&u, &h, 4);
    return u;
}
// single-instruction RNE f32->bf16 via the packed builtin (low half)
static __device__ __forceinline__ unsigned short f2bf(float x) {
    return (unsigned short)pk2bf(x, x);
}
static __device__ __forceinline__ float leakyf(float x) {
    return fmaxf(x, 0.01f * x);
}

// ============ Kernel 1: proj + per-node partial sums + pack + zero ============
// 512 blocks: n = bx>>2, b-quarter q = bx&3 (16 rows). 256 thr.
__global__ __launch_bounds__(256) void proj_kernel(
    const float* __restrict__ inputs, const float* __restrict__ W1,
    const float* __restrict__ b1,
    const float* __restrict__ W2, const float* __restrict__ W3,
    float* __restrict__ AT, float* __restrict__ BT,
    unsigned short* __restrict__ ATh, unsigned short* __restrict__ BTh,
    float* __restrict__ SQp,
    unsigned short* __restrict__ W2p, unsigned short* __restrict__ W3p,
    float* __restrict__ fpartA, float* __restrict__ fpartB)
{
    __shared__ float Xs[16 * 33];
    __shared__ float W1s[2048];
    __shared__ float red[16];

    int tid = threadIdx.x;
    int n = blockIdx.x >> 2, q = blockIdx.x & 3;

    for (int idx = tid; idx < 2048; idx += 256) W1s[idx] = W1[idx];
    for (int idx = tid; idx < 512; idx += 256) {
        int r = idx >> 5, d = idx & 31;
        Xs[r * 33 + d] = inputs[(q * 16 + r) * 4096 + n * 32 + d];
    }
    __syncthreads();

    int j = tid & 31, rb = tid >> 5;
    int lane = tid & 63, w = tid >> 6;
    float b1j = b1[j];
    float sa = 0.f, qa = 0.f, sb = 0.f, qb = 0.f;
    #pragma unroll
    for (int i = 0; i < 2; ++i) {
        int r = rb * 2 + i;
        int b = q * 16 + r;
        float a = b1j, c = 0.f;
        #pragma unroll
        for (int k = 0; k < 32; ++k) {
            float x = Xs[r * 33 + k];
            a += x * W1s[k * 32 + j];
            c += x * W1s[(32 + k) * 32 + j];
        }
        int off = (n * 64 + b) * 32 + j;
        AT[off] = a;  BT[off] = c;
        ATh[off] = f2bf(a);  BTh[off] = f2bf(c);
        sa += a; qa += a * a; sb += c; qb += c * c;
    }
    #pragma unroll
    for (int d = 32; d > 0; d >>= 1) {
        sa += __shfl_down(sa, d, 64);
        qa += __shfl_down(qa, d, 64);
        sb += __shfl_down(sb, d, 64);
        qb += __shfl_down(qb, d, 64);
    }
    if (lane == 0) { red[w*4+0] = sa; red[w*4+1] = qa; red[w*4+2] = sb; red[w*4+3] = qb; }
    __syncthreads();
    if (tid == 0) {
        float4 v;
        v.x = red[0] + red[4] + red[8]  + red[12];
        v.y = red[1] + red[5] + red[9]  + red[13];
        v.z = red[2] + red[6] + red[10] + red[14];
        v.w = red[3] + red[7] + red[11] + red[15];
        ((float4*)SQp)[n * 4 + q] = v;
    }

    if (blockIdx.x == 0 && tid < 64) {      // pack W2/W3 -> bf16 B-frag layout
        int l = tid, nn2 = l & 15, kc = l >> 4;
        #pragma unroll
        for (int ct = 0; ct < 2; ++ct)
            #pragma unroll
            for (int jj = 0; jj < 8; ++jj) {
                int k = kc * 8 + jj;
                W2p[(ct * 64 + l) * 8 + jj] = f2bf(W2[k * 32 + ct * 16 + nn2]);
            }
        #pragma unroll
        for (int ct = 0; ct < 3; ++ct)
            #pragma unroll
            for (int jj = 0; jj < 8; ++jj) {
                int k = kc * 8 + jj;
                int c2 = ct * 16 + nn2;
                W3p[(ct * 64 + l) * 8 + jj] = f2bf(c2 < 33 ? W3[k * 33 + c2] : 0.f);
            }
    }
    if (blockIdx.x == 1) {
        for (int idx = tid; idx < 1024; idx += 256) {
            fpartA[idx] = 0.f;
            fpartB[idx] = 0.f;
        }
    }
}

// ============ Kernel 2: LN stats via bf16 MFMA cross-GEMM ============
// 64 blocks: 16x16 (s,t) tile; 4 waves split K=2048; dual accumulators.
__global__ __launch_bounds__(256) void stats2_kernel(
    const unsigned short* __restrict__ ATh, const unsigned short* __restrict__ BTh,
    const float* __restrict__ SQp,
    const float* __restrict__ g1, const float* __restrict__ be1,
    float* __restrict__ statAB)
{
    __shared__ __align__(16) float part[4 * 64 * 4];
    int tid = threadIdx.x;
    int lane = tid & 63, w = tid >> 6;
    int s0 = (blockIdx.x >> 3) * 16, t0 = (blockIdx.x & 7) * 16;

    int m = lane & 15, kc = lane >> 4;
    const unsigned short* abase = ATh + (s0 + m) * 2048 + kc * 8 + w * 512;
    const unsigned short* bbase = BTh + (t0 + m) * 2048 + kc * 8 + w * 512;

    f32x4 acc0 = {0.f, 0.f, 0.f, 0.f}, acc1 = {0.f, 0.f, 0.f, 0.f};
    #pragma unroll
    for (int step = 0; step < 8; ++step) {
        bf16x8 av0 = *(const bf16x8*)(abase + (2 * step) * 32);
        bf16x8 bv0 = *(const bf16x8*)(bbase + (2 * step) * 32);
        acc0 = __builtin_amdgcn_mfma_f32_16x16x32_bf16(av0, bv0, acc0, 0, 0, 0);
        bf16x8 av1 = *(const bf16x8*)(abase + (2 * step + 1) * 32);
        bf16x8 bv1 = *(const bf16x8*)(bbase + (2 * step + 1) * 32);
        acc1 = __builtin_amdgcn_mfma_f32_16x16x32_bf16(av1, bv1, acc1, 0, 0, 0);
    }
    f32x4 acc;
    acc[0] = acc0[0] + acc1[0]; acc[1] = acc0[1] + acc1[1];
    acc[2] = acc0[2] + acc1[2]; acc[3] = acc0[3] + acc1[3];
    *(f32x4*)&part[(w * 64 + lane) * 4] = acc;
    __syncthreads();

    if (w == 0) {
        #pragma unroll
        for (int ww = 1; ww < 4; ++ww) {
            f32x4 o2 = *(const f32x4*)&part[(ww * 64 + lane) * 4];
            acc[0] += o2[0]; acc[1] += o2[1]; acc[2] += o2[2]; acc[3] += o2[3];
        }
        int col = lane & 15, quad = lane >> 4;
        int t = t0 + col;
        float sbt = 0.f, qbt = 0.f;
        #pragma unroll
        for (int o2 = 0; o2 < 4; ++o2) {
            float4 v = ((const float4*)SQp)[t * 4 + o2];
            sbt += v.z; qbt += v.w;
        }
        #pragma unroll
        for (int r = 0; r < 4; ++r) {
            int s = s0 + quad * 4 + r;
            if (s != t) {
                float sas = 0.f, qas = 0.f;
                #pragma unroll
                for (int o2 = 0; o2 < 4; ++o2) {
                    float4 v = ((const float4*)SQp)[s * 4 + o2];
                    sas += v.x; qas += v.y;
                }
                int e = t - (t > s);
                int p = s * 127 + e;
                float S = sas + sbt;
                float Q = qas + qbt + 2.f * acc[r];
                float mean = S * (1.f / 2048.f);
                float var  = Q * (1.f / 2048.f) - mean * mean;
                float inv  = rsqrtf(var + EPSF);
                float sc   = inv * g1[p];
                float2 o;
                o.x = sc;
                o.y = be1[p] - mean * sc;
                ((float2*)statAB)[p] = o;
            }
        }
    }
}

// ============ Kernel 3: edge MLP, NB=2 batches per block =====================
// 4096 blocks: s = bx&127, batch pair bp = bx>>7 -> b0=2bp, b0+1.
// Per block: stats/weights/Wf1/biases loaded ONCE, serve both batches.
// Hs: 80-B row stride (no XOR) -> write conflicts 8->4-way, aligned b128 read.
// Sigmoids go through edgebuf (LDS): 1 ds_write_b128 + broadcast ds_read_b128
// replaces 4 __shfl; coalesced edges_out store after the single barrier.
__global__ __launch_bounds__(256, 4) void edges_kernel(
    const float* __restrict__ AT, const float* __restrict__ BT,
    const float* __restrict__ statAB,
    const unsigned short* __restrict__ W2p, const unsigned short* __restrict__ W3p,
    const float* __restrict__ b2, const float* __restrict__ b3,
    const float* __restrict__ inputs, const float* __restrict__ Wf1,
    const float* __restrict__ bf1,
    float* __restrict__ edges_out,
    float* __restrict__ f, float* __restrict__ fpartA, float* __restrict__ fpartB)
{
    __shared__ __align__(16) unsigned short Hs[4][16 * 40];   // 5120 B
    __shared__ float Wf1s[1024];
    __shared__ float aggbuf[2][4][32];
    __shared__ __align__(16) float edgebuf[2][128];

    int tid = threadIdx.x;
    int s  = blockIdx.x & 127;
    int b0 = (blockIdx.x >> 7) * 2;
    int lane = tid & 63, w = tid >> 6;
    int m = lane & 15;          // A-frag row within tile / C-frag col
    int kb = lane >> 4;         // k-block (8 wide)
    int col = m;
    int q4 = kb * 4;            // C-frag row group

    for (int idx = tid; idx < 1024; idx += 256) Wf1s[idx] = Wf1[idx];

    // B fragments + biases (block-invariant)
    bf16x8 wb2[2], wb3[3];
    wb2[0] = *(const bf16x8*)(W2p + (0 * 64 + lane) * 8);
    wb2[1] = *(const bf16x8*)(W2p + (1 * 64 + lane) * 8);
    wb3[0] = *(const bf16x8*)(W3p + (0 * 64 + lane) * 8);
    wb3[1] = *(const bf16x8*)(W3p + (1 * 64 + lane) * 8);
    wb3[2] = *(const bf16x8*)(W3p + (2 * 64 + lane) * 8);
    float b2c0 = b2[col], b2c1 = b2[16 + col];
    float b3c[3];
    #pragma unroll
    for (int ct = 0; ct < 3; ++ct) {
        int c = ct * 16 + col;
        b3c[ct] = (c < 33) ? b3[c] : 0.f;
    }

    // A slices for both batches (32-bit offsets)
    f32x2 av[2][4];
    #pragma unroll
    for (int bi = 0; bi < 2; ++bi) {
        const float4* asl = (const float4*)(AT + (s * 64 + b0 + bi) * 32 + kb * 8);
        float4 a0 = asl[0], a1 = asl[1];
        av[bi][0][0]=a0.x; av[bi][0][1]=a0.y; av[bi][1][0]=a0.z; av[bi][1][1]=a0.w;
        av[bi][2][0]=a1.x; av[bi][2][1]=a1.y; av[bi][3][0]=a1.z; av[bi][3][1]=a1.w;
    }

    float aggpart[2][3] = {{0.f,0.f,0.f},{0.f,0.f,0.f}};

    #pragma unroll
    for (int rt = 0; rt < 2; ++rt) {
        int tile = w * 2 + rt;
        int e = tile * 16 + m;
        bool valid = (e < 127);
        int ee = valid ? e : 0;
        int t = ee + (ee >= s);
        // one stat load serves BOTH batches
        float2 st = ((const float2*)statAB)[s * 127 + ee];
        float sc = valid ? st.x : 0.f;
        float sh = valid ? st.y : 0.f;
        f32x2 sc2; sc2[0] = sc; sc2[1] = sc;
        f32x2 sh2; sh2[0] = sh; sh2[1] = sh;
        int grow0 = tile * 16 + q4;

        #pragma unroll
        for (int bi = 0; bi < 2; ++bi) {
            const float4* bsl = (const float4*)(BT + (t * 64 + b0 + bi) * 32 + kb * 8);
            float4 bv0 = bsl[0], bv1 = bsl[1];
            f32x2 bv[4];
            bv[0][0]=bv0.x; bv[0][1]=bv0.y; bv[1][0]=bv0.z; bv[1][1]=bv0.w;
            bv[2][0]=bv1.x; bv[2][1]=bv1.y; bv[3][0]=bv1.z; bv[3][1]=bv1.w;

            // LN-apply + leaky on packed f32 pairs
            union { bf16x8 v; unsigned u[4]; } AF;
            #pragma unroll
            for (int i = 0; i < 4; ++i) {
                f32x2 y = (av[bi][i] + bv[i]) * sc2 + sh2;
                f32x2 tq = y * 0.01f;
                float n0 = fmaxf(y[0], tq[0]);
                float n1 = fmaxf(y[1], tq[1]);
                AF.u[i] = pk2bf(n0, n1);
            }

            // GEMM2
            f32x4 c0 = {0.f, 0.f, 0.f, 0.f}, c1 = {0.f, 0.f, 0.f, 0.f};
            c0 = __builtin_amdgcn_mfma_f32_16x16x32_bf16(AF.v, wb2[0], c0, 0, 0, 0);
            c1 = __builtin_amdgcn_mfma_f32_16x16x32_bf16(AF.v, wb2[1], c1, 0, 0, 0);

            // C -> A transpose via wave-private scratch, 80-B row stride
            #pragma unroll
            for (int reg = 0; reg < 4; ++reg) {
                int row = q4 + reg;
                float x = leakyf(c0[reg] + b2c0);
                float y = leakyf(c1[reg] + b2c1);
                Hs[w][row * 40 + col]      = f2bf(x);
                Hs[w][row * 40 + col + 16] = f2bf(y);
            }
            // wave-synchronous read-back (16-B aligned: 80m + 16kb)
            bf16x8 a2 = *(const bf16x8*)&Hs[w][m * 40 + kb * 8];

            // GEMM3
            f32x4 oo[3];
            #pragma unroll
            for (int ct = 0; ct < 3; ++ct) {
                f32x4 cc = {0.f, 0.f, 0.f, 0.f};
                oo[ct] = __builtin_amdgcn_mfma_f32_16x16x32_bf16(a2, wb3[ct], cc, 0, 0, 0);
            }

            // sigmoid on col 0 -> edgebuf (one b128 write), broadcast read back
            if (col == 0) {
                float4 vv;
                vv.x = 1.f / (1.f + __expf(-(oo[0][0] + b3c[0])));
                vv.y = 1.f / (1.f + __expf(-(oo[0][1] + b3c[0])));
                vv.z = 1.f / (1.f + __expf(-(oo[0][2] + b3c[0])));
                vv.w = (grow0 == 124) ? 0.f
                     : 1.f / (1.f + __expf(-(oo[0][3] + b3c[0])));
                *(float4*)&edgebuf[bi][grow0] = vv;
            }
            f32x4 ev = *(const f32x4*)&edgebuf[bi][grow0];   // uniform per 16-lane group

            // agg partials (cols 1..32 of the 48-wide output)
            #pragma unroll
            for (int ct = 0; ct < 3; ++ct) {
                float bb3 = b3c[ct];
                float pt = ev[0] * (oo[ct][0] + bb3) + ev[1] * (oo[ct][1] + bb3)
                         + ev[2] * (oo[ct][2] + bb3) + ev[3] * (oo[ct][3] + bb3);
                aggpart[bi][ct] += pt;
            }
        }
    }

    // quad-reduce agg partials (sum over kb groups = rows), store wave slices
    #pragma unroll
    for (int bi = 0; bi < 2; ++bi)
        #pragma unroll
        for (int ct = 0; ct < 3; ++ct) {
            float pt = aggpart[bi][ct];
            pt += __shfl_xor(pt, 16, 64);
            pt += __shfl_xor(pt, 32, 64);
            int c = ct * 16 + col;
            if (kb == 0 && c >= 1 && c <= 32) aggbuf[bi][w][c - 1] = pt;
        }
    __syncthreads();                                   // the ONLY barrier

    // coalesced edges_out store (127 floats per (b,s))
    if (tid < 127)
        edges_out[b0 * PP + s * 127 + tid] = edgebuf[0][tid];
    else if (tid >= 128 && tid < 255)
        edges_out[(b0 + 1) * PP + s * 127 + (tid - 128)] = edgebuf[1][tid - 128];

    // f-row tails: wave 0 -> batch b0, wave 1 -> batch b0+1
    if (w < 2) {
        int bi = w;
        int j = lane & 15, kg = lane >> 4;
        int row = (b0 + bi) * 128 + s;
        const float* xrow = inputs + row * 32;
        float acc = 0.f;
        if (kg < 2) {
            #pragma unroll
            for (int i = 0; i < 16; ++i) {
                int k = kg * 16 + i;
                acc += xrow[k] * Wf1s[k * 16 + j];
            }
        } else {
            #pragma unroll
            for (int i = 0; i < 16; ++i) {
                int k = (kg - 2) * 16 + i;
                float tot = aggbuf[bi][0][k] + aggbuf[bi][1][k]
                          + aggbuf[bi][2][k] + aggbuf[bi][3][k];
                acc += tot * Wf1s[(32 + k) * 16 + j];
            }
        }
        acc += __shfl_xor(acc, 16, 64);
        acc += __shfl_xor(acc, 32, 64);
        if (lane < 16) {
            acc += bf1[j];
            f[row * 16 + j] = acc;
            int bucket = (blockIdx.x * 2 + bi) & 63;
            atomicAdd(&fpartA[bucket * 16 + j], acc);
            atomicAdd(&fpartB[bucket * 16 + j], acc * acc);
        }
    }
}

// ============ Kernel 4: f-stats reduce (redundant per block) + out ============
__global__ __launch_bounds__(256) void out_kernel(
    const float* __restrict__ f,
    const float* __restrict__ fpartA, const float* __restrict__ fpartB,
    const float* __restrict__ gf, const float* __restrict__ bef,
    const float* __restrict__ Wf2, const float* __restrict__ bf2,
    float* __restrict__ outp)
{
    __shared__ float Wf2s[512];
    __shared__ float sc[16], sh[16];
    __shared__ float fs[128];

    int tid = threadIdx.x;
    for (int idx = tid; idx < 512; idx += 256) Wf2s[idx] = Wf2[idx];
    if (tid < 16) {
        float S = 0.f, Q = 0.f;
        #pragma unroll
        for (int g = 0; g < 64; ++g) {
            S += fpartA[g * 16 + tid];
            Q += fpartB[g * 16 + tid];
        }
        float mean = S * (1.f / 8192.f);
        float var  = Q * (1.f / 8192.f) - mean * mean;
        float inv  = rsqrtf(var + EPSF);
        float s2   = inv * gf[tid];
        sc[tid] = s2;
        sh[tid] = bef[tid] - mean * s2;
    }
    int row0 = blockIdx.x * 8;
    if (tid < 128) {
        int r = tid >> 4, j = tid & 15;
        fs[r * 16 + j] = f[(row0 + r) * 16 + j];
    }
    __syncthreads();

    int rl = tid >> 5, d = tid & 31;
    float acc = bf2[d];
    #pragma unroll
    for (int j = 0; j < 16; ++j) {
        float v = fs[rl * 16 + j] * sc[j] + sh[j];
        v = leakyf(v);
        acc += v * Wf2s[j * 32 + d];
    }
    outp[(row0 + rl) * 32 + d] = acc;
}

extern "C" void kernel_launch(void* const* d_in, const int* in_sizes, int n_in,
                              void* d_out, int out_size, void* d_ws, size_t ws_size,
                              hipStream_t stream) {
    const float* inputs = (const float*)d_in[0];
    const float* W1   = (const float*)d_in[3];
    const float* b1   = (const float*)d_in[4];
    const float* g1   = (const float*)d_in[5];
    const float* be1  = (const float*)d_in[6];
    const float* W2   = (const float*)d_in[7];
    const float* b2   = (const float*)d_in[8];
    const float* W3   = (const float*)d_in[9];
    const float* b3   = (const float*)d_in[10];
    const float* Wf1  = (const float*)d_in[11];
    const float* bf1  = (const float*)d_in[12];
    const float* gf   = (const float*)d_in[13];
    const float* bef  = (const float*)d_in[14];
    const float* Wf2  = (const float*)d_in[15];
    const float* bf2  = (const float*)d_in[16];

    float* ws = (float*)d_ws;
    float* AT     = ws;                              // 262144
    float* BT     = ws + 262144;                     // 262144
    unsigned short* ATh = (unsigned short*)(ws + 524288);  // 262144 ush
    unsigned short* BTh = ATh + 262144;                    // 262144 ush
    float* SQp    = ws + 786432;                     // 2048 (128 n x 4 q x float4)
    float* statAB = ws + 790528;                     // 32512 (P x float2, interleaved)
    float* f      = ws + 823040;                     // 131072
    float* fpartA = ws + 954112;                     // 1024
    float* fpartB = ws + 955136;                     // 1024
    unsigned short* W2p = (unsigned short*)(ws + 956160);  // 1024 ush
    unsigned short* W3p = W2p + 1024;                      // 1536 ush

    float* edges_out = (float*)d_out;                    // B*P
    float* outp      = edges_out + (size_t)BB * PP;      // B*N*D

    proj_kernel<<<512, 256, 0, stream>>>(inputs, W1, b1, W2, W3,
                                         AT, BT, ATh, BTh, SQp,
                                         W2p, W3p, fpartA, fpartB);
    stats2_kernel<<<64, 256, 0, stream>>>(ATh, BTh, SQp, g1, be1, statAB);
    edges_kernel<<<4096, 256, 0, stream>>>(AT, BT, statAB, W2p, W3p,
                                           b2, b3, inputs, Wf1, bf1,
                                           edges_out, f, fpartA, fpartB);
    out_kernel<<<1024, 256, 0, stream>>>(f, fpartA, fpartB, gf, bef, Wf2, bf2, outp);
}

// Round 8
// 138.070 us; speedup vs baseline: 3.1892x; 1.0029x over previous
//
// GraphAndMessages optimized pipeline, rev7b (register-only GEMM2->GEMM3 chain).
// Identical semantics to rev6; source perturbed to defeat artifact caching.
#include <hip/hip_runtime.h>
#include <hip/hip_bf16.h>
#include <math.h>

#define BB 64
#define NN 128
#define DD 32
#define PP (NN * (NN - 1))   // 16256
#define EPSF 1e-5f

typedef __attribute__((ext_vector_type(8))) short bf16x8;
typedef __attribute__((ext_vector_type(4))) float f32x4;
typedef __attribute__((ext_vector_type(2))) float f32x2;

static __device__ __forceinline__ unsigned pk2bf(float a, float b) {
    float2 t; t.x = a; t.y = b;
    __hip_bfloat162 h = __float22bfloat162_rn(t);   // v_cvt_pk_bf16_f32
    unsigned u;
    __builtin_memcpy(&u, &h, 4);
    return u;
}
// single-instruction RNE f32->bf16 via the packed builtin (low half)
static __device__ __forceinline__ unsigned short f2bf(float x) {
    return (unsigned short)pk2bf(x, x);
}
static __device__ __forceinline__ float leakyf(float x) {
    return fmaxf(x, 0.01f * x);
}

// ============ Kernel 1: proj + per-node partial sums + pack + zero ============
// 512 blocks: n = bx>>2, b-quarter q = bx&3 (16 rows). 256 thr.
__global__ __launch_bounds__(256) void proj_kernel(
    const float* __restrict__ inputs, const float* __restrict__ W1,
    const float* __restrict__ b1,
    const float* __restrict__ W2, const float* __restrict__ W3,
    float* __restrict__ AT, float* __restrict__ BT,
    unsigned short* __restrict__ ATh, unsigned short* __restrict__ BTh,
    float* __restrict__ SQp,
    unsigned short* __restrict__ W2p, unsigned short* __restrict__ W3p,
    float* __restrict__ fpartA, float* __restrict__ fpartB)
{
    __shared__ float Xs[16 * 33];
    __shared__ float W1s[2048];
    __shared__ float red[16];

    int tid = threadIdx.x;
    int n = blockIdx.x >> 2, q = blockIdx.x & 3;

    for (int idx = tid; idx < 2048; idx += 256) W1s[idx] = W1[idx];
    for (int idx = tid; idx < 512; idx += 256) {
        int r = idx >> 5, d = idx & 31;
        Xs[r * 33 + d] = inputs[(q * 16 + r) * 4096 + n * 32 + d];
    }
    __syncthreads();

    int j = tid & 31, rb = tid >> 5;
    int lane = tid & 63, w = tid >> 6;
    float b1j = b1[j];
    float sa = 0.f, qa = 0.f, sb = 0.f, qb = 0.f;
    #pragma unroll
    for (int i = 0; i < 2; ++i) {
        int r = rb * 2 + i;
        int b = q * 16 + r;
        float a = b1j, c = 0.f;
        #pragma unroll
        for (int k = 0; k < 32; ++k) {
            float x = Xs[r * 33 + k];
            a += x * W1s[k * 32 + j];
            c += x * W1s[(32 + k) * 32 + j];
        }
        int off = (n * 64 + b) * 32 + j;
        AT[off] = a;  BT[off] = c;
        ATh[off] = f2bf(a);  BTh[off] = f2bf(c);
        sa += a; qa += a * a; sb += c; qb += c * c;
    }
    #pragma unroll
    for (int d = 32; d > 0; d >>= 1) {
        sa += __shfl_down(sa, d, 64);
        qa += __shfl_down(qa, d, 64);
        sb += __shfl_down(sb, d, 64);
        qb += __shfl_down(qb, d, 64);
    }
    if (lane == 0) { red[w*4+0] = sa; red[w*4+1] = qa; red[w*4+2] = sb; red[w*4+3] = qb; }
    __syncthreads();
    if (tid == 0) {
        float4 v;
        v.x = red[0] + red[4] + red[8]  + red[12];
        v.y = red[1] + red[5] + red[9]  + red[13];
        v.z = red[2] + red[6] + red[10] + red[14];
        v.w = red[3] + red[7] + red[11] + red[15];
        ((float4*)SQp)[n * 4 + q] = v;
    }

    if (blockIdx.x == 0 && tid < 64) {      // pack W2/W3 -> bf16 B-frag layout
        int l = tid, nn2 = l & 15, kc = l >> 4;
        #pragma unroll
        for (int ct = 0; ct < 2; ++ct)
            #pragma unroll
            for (int jj = 0; jj < 8; ++jj) {
                int k = kc * 8 + jj;
                W2p[(ct * 64 + l) * 8 + jj] = f2bf(W2[k * 32 + ct * 16 + nn2]);
            }
        // W3p rows permuted to the swapped-GEMM2 in-register slot order:
        // slot j<4 <- channel 4*kc+j ; slot j>=4 <- channel 16+4*kc+(j-4).
        #pragma unroll
        for (int ct = 0; ct < 3; ++ct)
            #pragma unroll
            for (int jj = 0; jj < 8; ++jj) {
                int k = (jj < 4) ? (kc * 4 + jj) : (16 + kc * 4 + (jj - 4));
                int c2 = ct * 16 + nn2;
                W3p[(ct * 64 + l) * 8 + jj] = f2bf(c2 < 33 ? W3[k * 33 + c2] : 0.f);
            }
    }
    if (blockIdx.x == 1) {
        for (int idx = tid; idx < 1024; idx += 256) {
            fpartA[idx] = 0.f;
            fpartB[idx] = 0.f;
        }
    }
}

// ============ Kernel 2: LN stats via bf16 MFMA cross-GEMM ============
// 64 blocks: 16x16 (s,t) tile; 4 waves split K=2048; dual accumulators.
__global__ __launch_bounds__(256) void stats2_kernel(
    const unsigned short* __restrict__ ATh, const unsigned short* __restrict__ BTh,
    const float* __restrict__ SQp,
    const float* __restrict__ g1, const float* __restrict__ be1,
    float* __restrict__ statAB)
{
    __shared__ __align__(16) float part[4 * 64 * 4];
    int tid = threadIdx.x;
    int lane = tid & 63, w = tid >> 6;
    int s0 = (blockIdx.x >> 3) * 16, t0 = (blockIdx.x & 7) * 16;

    int m = lane & 15, kc = lane >> 4;
    const unsigned short* abase = ATh + (s0 + m) * 2048 + kc * 8 + w * 512;
    const unsigned short* bbase = BTh + (t0 + m) * 2048 + kc * 8 + w * 512;

    f32x4 acc0 = {0.f, 0.f, 0.f, 0.f}, acc1 = {0.f, 0.f, 0.f, 0.f};
    #pragma unroll
    for (int step = 0; step < 8; ++step) {
        bf16x8 av0 = *(const bf16x8*)(abase + (2 * step) * 32);
        bf16x8 bv0 = *(const bf16x8*)(bbase + (2 * step) * 32);
        acc0 = __builtin_amdgcn_mfma_f32_16x16x32_bf16(av0, bv0, acc0, 0, 0, 0);
        bf16x8 av1 = *(const bf16x8*)(abase + (2 * step + 1) * 32);
        bf16x8 bv1 = *(const bf16x8*)(bbase + (2 * step + 1) * 32);
        acc1 = __builtin_amdgcn_mfma_f32_16x16x32_bf16(av1, bv1, acc1, 0, 0, 0);
    }
    f32x4 acc;
    acc[0] = acc0[0] + acc1[0]; acc[1] = acc0[1] + acc1[1];
    acc[2] = acc0[2] + acc1[2]; acc[3] = acc0[3] + acc1[3];
    *(f32x4*)&part[(w * 64 + lane) * 4] = acc;
    __syncthreads();

    if (w == 0) {
        #pragma unroll
        for (int ww = 1; ww < 4; ++ww) {
            f32x4 o2 = *(const f32x4*)&part[(ww * 64 + lane) * 4];
            acc[0] += o2[0]; acc[1] += o2[1]; acc[2] += o2[2]; acc[3] += o2[3];
        }
        int col = lane & 15, quad = lane >> 4;
        int t = t0 + col;
        float sbt = 0.f, qbt = 0.f;
        #pragma unroll
        for (int o2 = 0; o2 < 4; ++o2) {
            float4 v = ((const float4*)SQp)[t * 4 + o2];
            sbt += v.z; qbt += v.w;
        }
        #pragma unroll
        for (int r = 0; r < 4; ++r) {
            int s = s0 + quad * 4 + r;
            if (s != t) {
                float sas = 0.f, qas = 0.f;
                #pragma unroll
                for (int o2 = 0; o2 < 4; ++o2) {
                    float4 v = ((const float4*)SQp)[s * 4 + o2];
                    sas += v.x; qas += v.y;
                }
                int e = t - (t > s);
                int p = s * 127 + e;
                float S = sas + sbt;
                float Q = qas + qbt + 2.f * acc[r];
                float mean = S * (1.f / 2048.f);
                float var  = Q * (1.f / 2048.f) - mean * mean;
                float inv  = rsqrtf(var + EPSF);
                float sc   = inv * g1[p];
                float2 o;
                o.x = sc;
                o.y = be1[p] - mean * sc;
                ((float2*)statAB)[p] = o;
            }
        }
    }
}

// ============ Kernel 3: edge MLP, NB=2, register-only GEMM2->GEMM3 ==========
// 4096 blocks: s = bx&127, batch pair bp = bx>>7 -> b0=2bp, b0+1.
// Swapped GEMM2: mfma(wb2, AF) yields D^T (cols = edges), feeding GEMM3's
// A-frag directly in registers; W3p row-permute absorbs the k-slot order.
__global__ __launch_bounds__(256, 4) void edges_kernel(
    const float* __restrict__ AT, const float* __restrict__ BT,
    const float* __restrict__ statAB,
    const unsigned short* __restrict__ W2p, const unsigned short* __restrict__ W3p,
    const float* __restrict__ b2, const float* __restrict__ b3,
    const float* __restrict__ inputs, const float* __restrict__ Wf1,
    const float* __restrict__ bf1,
    float* __restrict__ edges_out,
    float* __restrict__ f, float* __restrict__ fpartA, float* __restrict__ fpartB)
{
    __shared__ float Wf1s[1024];
    __shared__ float aggbuf[2][4][32];
    __shared__ __align__(16) float edgebuf[2][128];

    int tid = threadIdx.x;
    int s  = blockIdx.x & 127;
    int b0 = (blockIdx.x >> 7) * 2;
    int lane = tid & 63, wv = tid >> 6;
    int m = lane & 15;          // edge-in-tile (A/B frag index) / C-frag col
    int kb = lane >> 4;         // k-block
    int col = m;
    int q4 = kb * 4;            // C-frag row group

    for (int idx = tid; idx < 1024; idx += 256) Wf1s[idx] = Wf1[idx];

    // B fragments + biases (block-invariant)
    bf16x8 wb2[2], wb3[3];
    wb2[0] = *(const bf16x8*)(W2p + (0 * 64 + lane) * 8);
    wb2[1] = *(const bf16x8*)(W2p + (1 * 64 + lane) * 8);
    wb3[0] = *(const bf16x8*)(W3p + (0 * 64 + lane) * 8);
    wb3[1] = *(const bf16x8*)(W3p + (1 * 64 + lane) * 8);
    wb3[2] = *(const bf16x8*)(W3p + (2 * 64 + lane) * 8);
    // b2 per swapped-GEMM2 output rows: ct0 -> channels 4kb+r, ct1 -> 16+4kb+r
    float b2v[8];
    #pragma unroll
    for (int r = 0; r < 4; ++r) {
        b2v[r]     = b2[q4 + r];
        b2v[4 + r] = b2[16 + q4 + r];
    }
    float b3c[3];
    #pragma unroll
    for (int ct = 0; ct < 3; ++ct) {
        int c = ct * 16 + col;
        b3c[ct] = (c < 33) ? b3[c] : 0.f;
    }

    // A slices for both batches (32-bit offsets)
    f32x2 av[2][4];
    #pragma unroll
    for (int bi = 0; bi < 2; ++bi) {
        const float4* asl = (const float4*)(AT + (s * 64 + b0 + bi) * 32 + kb * 8);
        float4 a0 = asl[0], a1 = asl[1];
        av[bi][0][0]=a0.x; av[bi][0][1]=a0.y; av[bi][1][0]=a0.z; av[bi][1][1]=a0.w;
        av[bi][2][0]=a1.x; av[bi][2][1]=a1.y; av[bi][3][0]=a1.z; av[bi][3][1]=a1.w;
    }

    float aggpart[2][3] = {{0.f,0.f,0.f},{0.f,0.f,0.f}};

    #pragma unroll
    for (int rt = 0; rt < 2; ++rt) {
        int tile = wv * 2 + rt;
        int e = tile * 16 + m;
        bool valid = (e < 127);
        int ee = valid ? e : 0;
        int t = ee + (ee >= s);
        // one stat load serves BOTH batches
        float2 st = ((const float2*)statAB)[s * 127 + ee];
        float sc = valid ? st.x : 0.f;
        float sh = valid ? st.y : 0.f;
        f32x2 sc2; sc2[0] = sc; sc2[1] = sc;
        f32x2 sh2; sh2[0] = sh; sh2[1] = sh;
        int grow0 = tile * 16 + q4;

        #pragma unroll
        for (int bi = 0; bi < 2; ++bi) {
            const float4* bsl = (const float4*)(BT + (t * 64 + b0 + bi) * 32 + kb * 8);
            float4 bv0 = bsl[0], bv1 = bsl[1];
            f32x2 bv[4];
            bv[0][0]=bv0.x; bv[0][1]=bv0.y; bv[1][0]=bv0.z; bv[1][1]=bv0.w;
            bv[2][0]=bv1.x; bv[2][1]=bv1.y; bv[3][0]=bv1.z; bv[3][1]=bv1.w;

            // LN-apply + leaky on packed f32 pairs
            union { bf16x8 v; unsigned u[4]; } AF;
            #pragma unroll
            for (int i = 0; i < 4; ++i) {
                f32x2 y = (av[bi][i] + bv[i]) * sc2 + sh2;
                f32x2 tq = y * 0.01f;
                float n0 = fmaxf(y[0], tq[0]);
                float n1 = fmaxf(y[1], tq[1]);
                AF.u[i] = pk2bf(n0, n1);
            }

            // GEMM2 SWAPPED: D^T = W2^T @ h^T; cols (lane&15) = edges
            f32x4 c0 = {0.f, 0.f, 0.f, 0.f}, c1 = {0.f, 0.f, 0.f, 0.f};
            c0 = __builtin_amdgcn_mfma_f32_16x16x32_bf16(wb2[0], AF.v, c0, 0, 0, 0);
            c1 = __builtin_amdgcn_mfma_f32_16x16x32_bf16(wb2[1], AF.v, c1, 0, 0, 0);

            // bias + leaky + pack straight into the GEMM3 A-frag (in register)
            union { bf16x8 v; unsigned u[4]; } A3;
            A3.u[0] = pk2bf(leakyf(c0[0] + b2v[0]), leakyf(c0[1] + b2v[1]));
            A3.u[1] = pk2bf(leakyf(c0[2] + b2v[2]), leakyf(c0[3] + b2v[3]));
            A3.u[2] = pk2bf(leakyf(c1[0] + b2v[4]), leakyf(c1[1] + b2v[5]));
            A3.u[3] = pk2bf(leakyf(c1[2] + b2v[6]), leakyf(c1[3] + b2v[7]));

            // GEMM3 (W3p rows pre-permuted to this slot order)
            f32x4 oo[3];
            #pragma unroll
            for (int ct = 0; ct < 3; ++ct) {
                f32x4 cc = {0.f, 0.f, 0.f, 0.f};
                oo[ct] = __builtin_amdgcn_mfma_f32_16x16x32_bf16(A3.v, wb3[ct], cc, 0, 0, 0);
            }

            // sigmoid on col 0 -> edgebuf (one b128 write), broadcast read back
            if (col == 0) {
                float4 vv;
                vv.x = 1.f / (1.f + __expf(-(oo[0][0] + b3c[0])));
                vv.y = 1.f / (1.f + __expf(-(oo[0][1] + b3c[0])));
                vv.z = 1.f / (1.f + __expf(-(oo[0][2] + b3c[0])));
                vv.w = (grow0 == 124) ? 0.f
                     : 1.f / (1.f + __expf(-(oo[0][3] + b3c[0])));
                *(float4*)&edgebuf[bi][grow0] = vv;
            }
            f32x4 ev = *(const f32x4*)&edgebuf[bi][grow0];   // uniform per 16-lane group

            // agg partials (cols 1..32 of the 48-wide output)
            #pragma unroll
            for (int ct = 0; ct < 3; ++ct) {
                float bb3 = b3c[ct];
                float pt = ev[0] * (oo[ct][0] + bb3) + ev[1] * (oo[ct][1] + bb3)
                         + ev[2] * (oo[ct][2] + bb3) + ev[3] * (oo[ct][3] + bb3);
                aggpart[bi][ct] += pt;
            }
        }
    }

    // quad-reduce agg partials (sum over kb groups = rows), store wave slices
    #pragma unroll
    for (int bi = 0; bi < 2; ++bi)
        #pragma unroll
        for (int ct = 0; ct < 3; ++ct) {
            float pt = aggpart[bi][ct];
            pt += __shfl_xor(pt, 16, 64);
            pt += __shfl_xor(pt, 32, 64);
            int c = ct * 16 + col;
            if (kb == 0 && c >= 1 && c <= 32) aggbuf[bi][wv][c - 1] = pt;
        }
    __syncthreads();                                   // the ONLY barrier

    // coalesced edges_out store (127 floats per (b,s))
    if (tid < 127)
        edges_out[b0 * PP + s * 127 + tid] = edgebuf[0][tid];
    else if (tid >= 128 && tid < 255)
        edges_out[(b0 + 1) * PP + s * 127 + (tid - 128)] = edgebuf[1][tid - 128];

    // f-row tails: wave 0 -> batch b0, wave 1 -> batch b0+1
    if (wv < 2) {
        int bi = wv;
        int j = lane & 15, kg = lane >> 4;
        int row = (b0 + bi) * 128 + s;
        const float* xrow = inputs + row * 32;
        float acc = 0.f;
        if (kg < 2) {
            #pragma unroll
            for (int i = 0; i < 16; ++i) {
                int k = kg * 16 + i;
                acc += xrow[k] * Wf1s[k * 16 + j];
            }
        } else {
            #pragma unroll
            for (int i = 0; i < 16; ++i) {
                int k = (kg - 2) * 16 + i;
                float tot = aggbuf[bi][0][k] + aggbuf[bi][1][k]
                          + aggbuf[bi][2][k] + aggbuf[bi][3][k];
                acc += tot * Wf1s[(32 + k) * 16 + j];
            }
        }
        acc += __shfl_xor(acc, 16, 64);
        acc += __shfl_xor(acc, 32, 64);
        if (lane < 16) {
            acc += bf1[j];
            f[row * 16 + j] = acc;
            int bucket = (blockIdx.x * 2 + bi) & 63;
            atomicAdd(&fpartA[bucket * 16 + j], acc);
            atomicAdd(&fpartB[bucket * 16 + j], acc * acc);
        }
    }
}

// ============ Kernel 4: f-stats reduce (redundant per block) + out ============
__global__ __launch_bounds__(256) void out_kernel(
    const float* __restrict__ f,
    const float* __restrict__ fpartA, const float* __restrict__ fpartB,
    const float* __restrict__ gf, const float* __restrict__ bef,
    const float* __restrict__ Wf2, const float* __restrict__ bf2,
    float* __restrict__ outp)
{
    __shared__ float Wf2s[512];
    __shared__ float sc[16], sh[16];
    __shared__ float fs[128];

    int tid = threadIdx.x;
    for (int idx = tid; idx < 512; idx += 256) Wf2s[idx] = Wf2[idx];
    if (tid < 16) {
        float S = 0.f, Q = 0.f;
        #pragma unroll
        for (int g = 0; g < 64; ++g) {
            S += fpartA[g * 16 + tid];
            Q += fpartB[g * 16 + tid];
        }
        float mean = S * (1.f / 8192.f);
        float var  = Q * (1.f / 8192.f) - mean * mean;
        float inv  = rsqrtf(var + EPSF);
        float s2   = inv * gf[tid];
        sc[tid] = s2;
        sh[tid] = bef[tid] - mean * s2;
    }
    int row0 = blockIdx.x * 8;
    if (tid < 128) {
        int r = tid >> 4, j = tid & 15;
        fs[r * 16 + j] = f[(row0 + r) * 16 + j];
    }
    __syncthreads();

    int rl = tid >> 5, d = tid & 31;
    float acc = bf2[d];
    #pragma unroll
    for (int j = 0; j < 16; ++j) {
        float v = fs[rl * 16 + j] * sc[j] + sh[j];
        v = leakyf(v);
        acc += v * Wf2s[j * 32 + d];
    }
    outp[(row0 + rl) * 32 + d] = acc;
}

extern "C" void kernel_launch(void* const* d_in, const int* in_sizes, int n_in,
                              void* d_out, int out_size, void* d_ws, size_t ws_size,
                              hipStream_t stream) {
    const float* inputs = (const float*)d_in[0];
    const float* W1   = (const float*)d_in[3];
    const float* b1   = (const float*)d_in[4];
    const float* g1   = (const float*)d_in[5];
    const float* be1  = (const float*)d_in[6];
    const float* W2   = (const float*)d_in[7];
    const float* b2   = (const float*)d_in[8];
    const float* W3   = (const float*)d_in[9];
    const float* b3   = (const float*)d_in[10];
    const float* Wf1  = (const float*)d_in[11];
    const float* bf1  = (const float*)d_in[12];
    const float* gf   = (const float*)d_in[13];
    const float* bef  = (const float*)d_in[14];
    const float* Wf2  = (const float*)d_in[15];
    const float* bf2  = (const float*)d_in[16];

    float* ws = (float*)d_ws;
    float* AT     = ws;                              // 262144
    float* BT     = ws + 262144;                     // 262144
    unsigned short* ATh = (unsigned short*)(ws + 524288);  // 262144 ush
    unsigned short* BTh = ATh + 262144;                    // 262144 ush
    float* SQp    = ws + 786432;                     // 2048 (128 n x 4 q x float4)
    float* statAB = ws + 790528;                     // 32512 (P x float2, interleaved)
    float* f      = ws + 823040;                     // 131072
    float* fpartA = ws + 954112;                     // 1024
    float* fpartB = ws + 955136;                     // 1024
    unsigned short* W2p = (unsigned short*)(ws + 956160);  // 1024 ush
    unsigned short* W3p = W2p + 1024;                      // 1536 ush

    float* edges_out = (float*)d_out;                    // B*P
    float* outp      = edges_out + (size_t)BB * PP;      // B*N*D

    proj_kernel<<<512, 256, 0, stream>>>(inputs, W1, b1, W2, W3,
                                         AT, BT, ATh, BTh, SQp,
                                         W2p, W3p, fpartA, fpartB);
    stats2_kernel<<<64, 256, 0, stream>>>(ATh, BTh, SQp, g1, be1, statAB);
    edges_kernel<<<4096, 256, 0, stream>>>(AT, BT, statAB, W2p, W3p,
                                           b2, b3, inputs, Wf1, bf1,
                                           edges_out, f, fpartA, fpartB);
    out_kernel<<<1024, 256, 0, stream>>>(f, fpartA, fpartB, gf, bef, Wf2, bf2, outp);
}